// Round 11
// baseline (435.809 us; speedup 1.0000x reference)
//
#include <hip/hip_runtime.h>
#include <hip/hip_bf16.h>
#include <math.h>

#define BB 8
#define NN 2048
#define KK 20
#define UPF 2
#define CIN 256
#define DD 64
#define COUTN 128
#define PHH 64
#define AHH 256
#define BN_INV 0.9999950000374997f   // np.float32(1/sqrt(1+1e-5))
#define NPB 16                       // attn n's per block (16 waves)

typedef __hip_bfloat16 bf16;
typedef unsigned short u16;
typedef unsigned long long u64;
typedef _Float16 f16;
typedef _Float16 h2   __attribute__((ext_vector_type(2)));
typedef _Float16 f16x4 __attribute__((ext_vector_type(4)));
typedef _Float16 f16x8 __attribute__((ext_vector_type(8)));
typedef float    f32x4 __attribute__((ext_vector_type(4)));

static __device__ __forceinline__ float bf2f(const bf16 v) { return __bfloat162float(v); }
static __device__ __forceinline__ bf16  f2bf(const float v) { return __float2bfloat16(v); }
static __device__ __forceinline__ u16   f2bfu(const float v) {
    return __builtin_bit_cast(u16, __float2bfloat16(v));
}
// exact bf16(bits)->f32
static __device__ __forceinline__ float lo2f(const unsigned v) { return __builtin_bit_cast(float, v << 16); }
static __device__ __forceinline__ float hi2f(const unsigned v) { return __builtin_bit_cast(float, v & 0xFFFF0000u); }

static __device__ __forceinline__ f32x4 mfma16(const f16x8 a, const f16x8 b, const f32x4 c) {
    return __builtin_amdgcn_mfma_f32_16x16x32_f16(a, b, c, 0, 0, 0);
}
// order-preserving float->u32 map: ascending float => ascending unsigned.
static __device__ __forceinline__ unsigned fmap(const float f) {
    unsigned u = __builtin_bit_cast(unsigned, f);
    return (u >> 31) ? ~u : (u | 0x80000000u);
}

__global__ void sentinel_kernel(float* out) {
    if (threadIdx.x == 0 && blockIdx.x == 0) out[0] = 100.0f;
}

// ---------------------------------------------------------------------------
// Kernel 0: weight prep (f16 k-contiguous rows for MFMA; Wth transposed;
// A1s/A1b folded BN; Wendh f16 for the conv_end MFMA).
// ---------------------------------------------------------------------------
__global__ __launch_bounds__(256) void prep_kernel(
    const float* __restrict__ Wa1, const float* __restrict__ Wp2,
    const float* __restrict__ Wend, const float* __restrict__ Wt,
    const float* __restrict__ Wv1, const float* __restrict__ Wv2,
    const float* __restrict__ Wvs, const float* __restrict__ Wvv,
    const float* __restrict__ Wres,
    const float* __restrict__ Wk, const float* __restrict__ Wq,
    const float* __restrict__ Wu,
    const float* __restrict__ ba1, const float* __restrict__ ga1,
    const float* __restrict__ betaa1,
    f16* __restrict__ Wa1h, f16* __restrict__ Wp2h, f16* __restrict__ Wth,
    float* __restrict__ A1s, float* __restrict__ A1b,
    f16* __restrict__ Wendh,
    f16* __restrict__ Wv1h, f16* __restrict__ Wv2h, f16* __restrict__ Wvsh,
    f16* __restrict__ Wvvh, f16* __restrict__ Wresh,
    f16* __restrict__ Wkh, f16* __restrict__ Wqh, f16* __restrict__ Wuh) {
    const int t = blockIdx.x * 256 + threadIdx.x;
    if (t < AHH * DD)        Wa1h[t] = (f16)Wa1[t];
    if (t < PHH * DD)        Wp2h[t] = (f16)Wp2[t];
    if (t < COUTN * AHH)     { int cr = t >> 8, hh = t & 255; Wth[t] = (f16)Wt[hh * COUTN + cr]; }
    if (t < AHH) {
        float gsc = ga1[t] * BN_INV;
        A1s[t] = gsc;
        A1b[t] = gsc * ba1[t] + betaa1[t];
    }
    if (t < COUTN * DD)      Wendh[t] = (f16)Wend[t];
    if (t < CIN * 2 * CIN)   Wv1h[t] = (f16)Wv1[t];
    if (t < CIN * CIN)       Wv2h[t] = (f16)Wv2[t];
    if (t < CIN * 2 * CIN)   Wvsh[t] = (f16)Wvs[t];
    if (t < DD * CIN)        Wvvh[t] = (f16)Wvv[t];
    if (t < COUTN * CIN)     Wresh[t] = (f16)Wres[t];
    if (t < DD * CIN)        Wkh[t]  = (f16)Wk[t];
    if (t < DD * CIN)        Wqh[t]  = (f16)Wq[t];
    if (t < DD * CIN)        Wuh[t]  = (f16)Wu[t];
}

// ---------------------------------------------------------------------------
// Kernel 0b: transpose key/query/upfeat (B,C,N) fp32 -> point-major f16.
// ---------------------------------------------------------------------------
__global__ __launch_bounds__(256) void xpose_kernel(
    const float* __restrict__ key_feat, const float* __restrict__ query_feat,
    const float* __restrict__ upfeat,
    f16* __restrict__ xkqT, f16* __restrict__ xuT) {
    __shared__ float tile[64][65];
    const int b  = blockIdx.x >> 5;
    const int n0 = (blockIdx.x & 31) << 6;
    const int y  = blockIdx.y;
    const int src = y >> 2;
    const int ct  = (y & 3) << 6;
    const int t = threadIdx.x;
    const float* xin = (src == 0) ? key_feat : (src == 1) ? query_feat : upfeat;
    f16* dst; int CT, cb;
    if (src < 2) { dst = xkqT; CT = 512; cb = src * 256 + ct; }
    else         { dst = xuT;  CT = 256; cb = ct; }
    for (int u = t; u < 64 * 64; u += 256) {
        const int c = u >> 6, j = u & 63;
        tile[c][j] = xin[((size_t)b * CIN + ct + c) * NN + n0 + j];
    }
    __syncthreads();
    for (int u = t; u < 64 * 32; u += 256) {
        const int n = u >> 5, c0 = (u & 31) << 1;
        h2 pr; pr.x = (f16)tile[c0][n]; pr.y = (f16)tile[c0 + 1][n];
        ((unsigned*)dst)[(((size_t)b * NN + n0 + n) * CT + cb + c0) >> 1] =
            __builtin_bit_cast(unsigned, pr);
    }
}

// ---------------------------------------------------------------------------
// Kernel 1: KNN — block per query, adaptive single-histogram select
// (verified round 9; fallback = verified round-5 radix).
// ---------------------------------------------------------------------------
__global__ __launch_bounds__(256) void knn_kernel(const float* __restrict__ pos,
                                                  u16* __restrict__ idx_out,
                                                  float* __restrict__ posT) {
    __shared__ float dist[NN];
    __shared__ int   hist[512];
    __shared__ unsigned rmin[4], rmax[4];
    __shared__ u64   cbuf[64];
    __shared__ float q[3];
    __shared__ unsigned minkS;
    __shared__ int   shiftS, jstarS, cntS;
    __shared__ u64   ltbuf[KK];
    __shared__ int   tiebuf[64];
    __shared__ int   ri[4];
    __shared__ unsigned prefS;
    __shared__ int   knS, cnt_lt, cnt_eq;

    const int b = blockIdx.x / NN;
    const int n = blockIdx.x % NN;
    const int t = threadIdx.x;
    const float* pb = pos + (size_t)b * 3 * NN;
    const size_t rowKK = ((size_t)b * NN + n) * KK;

    if (t < 3) {
        float v = pb[(size_t)t * NN + n];
        q[t] = v;
        posT[((size_t)b * NN + n) * 3 + t] = v;
    }
    if (t == 0) { prefS = 0u; knS = KK; cnt_lt = 0; cnt_eq = 0; cntS = 0; jstarS = 0; }
    __syncthreads();
    const float qx = q[0], qy = q[1], qz = q[2];
    const float sqq = __fadd_rn(__fadd_rn(__fmul_rn(qx, qx), __fmul_rn(qy, qy)), __fmul_rn(qz, qz));
    unsigned kmin = 0xFFFFFFFFu, kmax = 0u;
    for (int m = t; m < NN; m += 256) {
        float px = pb[m];
        float py = pb[NN + m];
        float pz = pb[2 * NN + m];
        float sqm = __fadd_rn(__fadd_rn(__fmul_rn(px, px), __fmul_rn(py, py)), __fmul_rn(pz, pz));
        float dt  = __fadd_rn(__fadd_rn(__fmul_rn(qx, px), __fmul_rn(qy, py)), __fmul_rn(qz, pz));
        const float d = __fsub_rn(__fadd_rn(sqq, sqm), __fmul_rn(2.0f, dt));
        dist[m] = d;
        const unsigned key = fmap(d);
        kmin = min(kmin, key);
        kmax = max(kmax, key);
    }
#pragma unroll
    for (int off = 32; off > 0; off >>= 1) {
        kmin = min(kmin, (unsigned)__shfl_down((int)kmin, off, 64));
        kmax = max(kmax, (unsigned)__shfl_down((int)kmax, off, 64));
    }
    if ((t & 63) == 0) { rmin[t >> 6] = kmin; rmax[t >> 6] = kmax; }
    hist[t] = 0; hist[256 + t] = 0;
    __syncthreads();
    if (t == 0) {
        const unsigned mn = min(min(rmin[0], rmin[1]), min(rmin[2], rmin[3]));
        const unsigned mx = max(max(rmax[0], rmax[1]), max(rmax[2], rmax[3]));
        const unsigned range = mx - mn;
        minkS  = mn;
        shiftS = (range >= 256u) ? (24 - __clz((int)range)) : 0;
    }
    __syncthreads();
    const unsigned mink = minkS;
    const int sh = shiftS;

    for (int m = t; m < NN; m += 256) {
        const unsigned bin = (fmap(dist[m]) - mink) >> sh;
        atomicAdd(&hist[((unsigned)(t & 1) << 8) | bin], 1);
    }
    __syncthreads();
    if (t < 64) {
        const int h0  = hist[4 * t + 0] + hist[256 + 4 * t + 0];
        const int h1  = hist[4 * t + 1] + hist[256 + 4 * t + 1];
        const int h2v = hist[4 * t + 2] + hist[256 + 4 * t + 2];
        const int h3  = hist[4 * t + 3] + hist[256 + 4 * t + 3];
        const int lsum = h0 + h1 + h2v + h3;
        int incl = lsum;
#pragma unroll
        for (int off = 1; off < 64; off <<= 1) {
            int v = __shfl_up(incl, off, 64);
            if (t >= off) incl += v;
        }
        const int excl = incl - lsum;
        if (excl < KK && excl + lsum >= KK) {
            int bsel;
            if      (excl + h0 >= KK)            bsel = 0;
            else if (excl + h0 + h1 >= KK)       bsel = 1;
            else if (excl + h0 + h1 + h2v >= KK) bsel = 2;
            else                                 bsel = 3;
            jstarS = 4 * t + bsel;
        }
    }
    __syncthreads();
    const unsigned jstar = (unsigned)jstarS;

    for (int m = t; m < NN; m += 256) {
        const unsigned key = fmap(dist[m]);
        if (((key - mink) >> sh) <= jstar) {
            const int p = atomicAdd(&cntS, 1);
            if (p < 64) cbuf[p] = ((u64)key << 32) | (unsigned)m;
        }
    }
    __syncthreads();
    const int total = cntS;

    if (total <= 64) {
        if (t < 64) {
            u64 v = (t < total) ? cbuf[t] : 0xFFFFFFFFFFFFFFFFull;
            int rank = 0;
#pragma unroll 16
            for (int j = 0; j < 64; ++j) {
                const u64 o = (u64)__shfl((long long)v, j, 64);
                if (o < v) ++rank;
            }
            if (t < total && rank < KK) idx_out[rowKK + rank] = (u16)(v & 0xFFFFu);
        }
        return;
    }

    // ---- fallback: verified 4-pass radix select ----
    for (int pass = 0; pass < 4; ++pass) {
        const int shift = 24 - 8 * pass;
        const unsigned pm = (pass == 0) ? 0u : (0xFFFFFFFFu << (32 - 8 * pass));
        hist[t] = 0;
        __syncthreads();
        const unsigned pref = prefS;
        const int kn = knS;
        for (int m = t; m < NN; m += 256) {
            unsigned key = fmap(dist[m]);
            if ((key & pm) == pref)
                atomicAdd(&hist[(key >> shift) & 255], 1);
        }
        __syncthreads();
        if (t < 64) {
            const int h0 = hist[4 * t + 0], h1 = hist[4 * t + 1];
            const int h2v = hist[4 * t + 2], h3 = hist[4 * t + 3];
            const int lsum = h0 + h1 + h2v + h3;
            int incl = lsum;
#pragma unroll
            for (int off = 1; off < 64; off <<= 1) {
                int v = __shfl_up(incl, off, 64);
                if (t >= off) incl += v;
            }
            const int excl = incl - lsum;
            if (excl < kn && excl + lsum >= kn) {
                int bsel, cb;
                if      (excl + h0 >= kn)            { bsel = 0; cb = excl; }
                else if (excl + h0 + h1 >= kn)       { bsel = 1; cb = excl + h0; }
                else if (excl + h0 + h1 + h2v >= kn) { bsel = 2; cb = excl + h0 + h1; }
                else                                 { bsel = 3; cb = excl + h0 + h1 + h2v; }
                knS = kn - cb;
                prefS = pref | ((unsigned)(4 * t + bsel) << shift);
            }
        }
        __syncthreads();
    }

    const unsigned T = prefS;
    for (int m = t; m < NN; m += 256) {
        unsigned key = fmap(dist[m]);
        if (key < T) {
            int p = atomicAdd(&cnt_lt, 1);
            ltbuf[p] = ((u64)key << 32) | (unsigned)m;
        } else if (key == T) {
            int p = atomicAdd(&cnt_eq, 1);
            if (p < 64) tiebuf[p] = m;
        }
    }
    __syncthreads();
    const int nlt = cnt_lt, neq_need = knS, ceq = cnt_eq;

    if (t < 64) {
        u64 v = (t < nlt) ? ltbuf[t] : 0xFFFFFFFFFFFFFFFFull;
        int rank = 0;
#pragma unroll
        for (int j = 0; j < KK; ++j) {
            const u64 o = (u64)__shfl((long long)v, j, 64);
            if (o < v) ++rank;
        }
        if (t < nlt) idx_out[rowKK + rank] = (u16)(v & 0xFFFFu);
    }
    if (ceq <= 64) {
        if (t < 64) {
            int ti = (t < ceq) ? tiebuf[t] : 0x7FFFFFFF;
            int rk = 0;
            for (int j = 0; j < 64; ++j) {
                const int o = __shfl(ti, j, 64);
                if (o < ti) ++rk;
            }
            if (t < ceq && rk < neq_need) idx_out[rowKK + nlt + rk] = (u16)ti;
        }
    } else {
        for (int iter = 0; iter < neq_need; ++iter) {
            int bi = NN;
            for (int m = t; m < NN; m += 256)
                if (fmap(dist[m]) == T && m < bi) bi = m;
            for (int off = 32; off > 0; off >>= 1) {
                int i2 = __shfl_down(bi, off, 64);
                bi = min(bi, i2);
            }
            if ((t & 63) == 0) ri[t >> 6] = bi;
            __syncthreads();
            if (t == 0) {
                int i0 = min(min(ri[0], ri[1]), min(ri[2], ri[3]));
                idx_out[rowKK + nlt + iter] = (u16)i0;
                dist[i0] = 3.4e38f;
            }
            __syncthreads();
        }
    }
}

// ---------------------------------------------------------------------------
// Kernel 2 (MFMA): value path + fused kf/qf/uf projections (verified r10).
// ---------------------------------------------------------------------------
__global__ __launch_bounds__(256) void value_mfma(
    const f16* __restrict__ xkqT, const f16* __restrict__ xuT,
    const f16* __restrict__ Wv1h, const float* __restrict__ bv1,
    const f16* __restrict__ Wv2h, const float* __restrict__ bv2,
    const f16* __restrict__ Wvsh, const float* __restrict__ bvs,
    const f16* __restrict__ Wvvh, const float* __restrict__ bvv,
    const f16* __restrict__ Wresh, const float* __restrict__ bres,
    const f16* __restrict__ Wkh, const float* __restrict__ bk,
    const f16* __restrict__ Wqh, const float* __restrict__ bq,
    const f16* __restrict__ Wuh, const float* __restrict__ bu,
    bf16* __restrict__ vf_ws, bf16* __restrict__ resid_ws,
    bf16* __restrict__ kf, bf16* __restrict__ qf, bf16* __restrict__ uf) {
    __shared__ __align__(16) char hv[32 * 512];
    const int b  = blockIdx.x >> 6;
    const int n0 = (blockIdx.x & 63) << 5;
    const int t = threadIdx.x;
    const int w = t >> 6, l = t & 63, g = l >> 4, li = l & 15;
    const f16* xb = xkqT + ((size_t)b * NN + n0) * 512;
    const f32x4 zero4 = {0.f, 0.f, 0.f, 0.f};

    f32x4 a1[4][2];
    f32x4 ak[2] = {zero4, zero4}, aq[2] = {zero4, zero4};
#pragma unroll
    for (int mt = 0; mt < 4; ++mt) { a1[mt][0] = zero4; a1[mt][1] = zero4; }
    for (int ks = 0; ks < 16; ++ks) {
        f16x8 bx0 = *(const f16x8*)(xb + (size_t)li * 512 + ks * 32 + g * 8);
        f16x8 bx1 = *(const f16x8*)(xb + (size_t)(16 + li) * 512 + ks * 32 + g * 8);
#pragma unroll
        for (int mt = 0; mt < 4; ++mt) {
            const f16x8 af = *(const f16x8*)(Wv1h + (size_t)(w * 64 + mt * 16 + li) * 512 + ks * 32 + g * 8);
            a1[mt][0] = mfma16(af, bx0, a1[mt][0]);
            a1[mt][1] = mfma16(af, bx1, a1[mt][1]);
        }
        if (ks < 8) {
            const f16x8 afk = *(const f16x8*)(Wkh + (size_t)(w * 16 + li) * 256 + ks * 32 + g * 8);
            ak[0] = mfma16(afk, bx0, ak[0]);
            ak[1] = mfma16(afk, bx1, ak[1]);
        } else {
            const f16x8 afq = *(const f16x8*)(Wqh + (size_t)(w * 16 + li) * 256 + (ks - 8) * 32 + g * 8);
            aq[0] = mfma16(afq, bx0, aq[0]);
            aq[1] = mfma16(afq, bx1, aq[1]);
        }
    }
    f32x4 au[2] = {zero4, zero4};
    {
        const f16* xub = xuT + ((size_t)b * NN + n0) * 256;
        for (int ks = 0; ks < 8; ++ks) {
            f16x8 bu0 = *(const f16x8*)(xub + (size_t)li * 256 + ks * 32 + g * 8);
            f16x8 bu1 = *(const f16x8*)(xub + (size_t)(16 + li) * 256 + ks * 32 + g * 8);
            const f16x8 af = *(const f16x8*)(Wuh + (size_t)(w * 16 + li) * 256 + ks * 32 + g * 8);
            au[0] = mfma16(af, bu0, au[0]);
            au[1] = mfma16(af, bu1, au[1]);
        }
    }
#pragma unroll
    for (int mt = 0; mt < 4; ++mt) {
        const int ch0 = w * 64 + mt * 16 + g * 4;
        const float4 b4 = *(const float4*)(bv1 + ch0);
#pragma unroll
        for (int nt = 0; nt < 2; ++nt) {
            const int n = nt * 16 + li;
            f16x4 px;
            px.x = (f16)fmaxf(a1[mt][nt][0] + b4.x, 0.f);
            px.y = (f16)fmaxf(a1[mt][nt][1] + b4.y, 0.f);
            px.z = (f16)fmaxf(a1[mt][nt][2] + b4.z, 0.f);
            px.w = (f16)fmaxf(a1[mt][nt][3] + b4.w, 0.f);
            *(f16x4*)(hv + n * 512 + ((ch0 * 2) ^ ((n & 7) << 4))) = px;
        }
    }
    {
        const int ch0 = w * 16 + g * 4;
        const float4 bk4 = *(const float4*)(bk + ch0);
        const float4 bq4 = *(const float4*)(bq + ch0);
        const float4 bu4 = *(const float4*)(bu + ch0);
#pragma unroll
        for (int nt = 0; nt < 2; ++nt) {
            const int n = nt * 16 + li;
            const size_t base = ((size_t)b * NN + n0 + n) * DD + ch0;
            ushort4 pk, pq, pu;
            pk.x = f2bfu(ak[nt][0] + bk4.x); pk.y = f2bfu(ak[nt][1] + bk4.y);
            pk.z = f2bfu(ak[nt][2] + bk4.z); pk.w = f2bfu(ak[nt][3] + bk4.w);
            pq.x = f2bfu(aq[nt][0] + bq4.x); pq.y = f2bfu(aq[nt][1] + bq4.y);
            pq.z = f2bfu(aq[nt][2] + bq4.z); pq.w = f2bfu(aq[nt][3] + bq4.w);
            pu.x = f2bfu(au[nt][0] + bu4.x); pu.y = f2bfu(au[nt][1] + bu4.y);
            pu.z = f2bfu(au[nt][2] + bu4.z); pu.w = f2bfu(au[nt][3] + bu4.w);
            *(ushort4*)((char*)kf + base * 2) = pk;
            *(ushort4*)((char*)qf + base * 2) = pq;
            *(ushort4*)((char*)uf + base * 2) = pu;
        }
    }
    __syncthreads();

    f32x4 a2[4][2];
#pragma unroll
    for (int mt = 0; mt < 4; ++mt) { a2[mt][0] = zero4; a2[mt][1] = zero4; }
    for (int ks = 0; ks < 8; ++ks) {
        f16x8 bh[2];
#pragma unroll
        for (int nt = 0; nt < 2; ++nt) {
            const int n = nt * 16 + li;
            bh[nt] = *(const f16x8*)(hv + n * 512 + ((ks * 64 + g * 16) ^ ((n & 7) << 4)));
        }
#pragma unroll
        for (int mt = 0; mt < 4; ++mt) {
            const f16x8 af = *(const f16x8*)(Wv2h + (size_t)(w * 64 + mt * 16 + li) * 256 + ks * 32 + g * 8);
            a2[mt][0] = mfma16(af, bh[0], a2[mt][0]);
            a2[mt][1] = mfma16(af, bh[1], a2[mt][1]);
        }
    }
    for (int ks = 0; ks < 16; ++ks) {
        f16x8 bx0 = *(const f16x8*)(xb + (size_t)li * 512 + ks * 32 + g * 8);
        f16x8 bx1 = *(const f16x8*)(xb + (size_t)(16 + li) * 512 + ks * 32 + g * 8);
#pragma unroll
        for (int mt = 0; mt < 4; ++mt) {
            const f16x8 af = *(const f16x8*)(Wvsh + (size_t)(w * 64 + mt * 16 + li) * 512 + ks * 32 + g * 8);
            a2[mt][0] = mfma16(af, bx0, a2[mt][0]);
            a2[mt][1] = mfma16(af, bx1, a2[mt][1]);
        }
    }
    __syncthreads();
#pragma unroll
    for (int mt = 0; mt < 4; ++mt) {
        const int ch0 = w * 64 + mt * 16 + g * 4;
        const float4 c4a = *(const float4*)(bv2 + ch0);
        const float4 c4b = *(const float4*)(bvs + ch0);
#pragma unroll
        for (int nt = 0; nt < 2; ++nt) {
            const int n = nt * 16 + li;
            f16x4 px;
            px.x = (f16)(a2[mt][nt][0] + c4a.x + c4b.x);
            px.y = (f16)(a2[mt][nt][1] + c4a.y + c4b.y);
            px.z = (f16)(a2[mt][nt][2] + c4a.z + c4b.z);
            px.w = (f16)(a2[mt][nt][3] + c4a.w + c4b.w);
            *(f16x4*)(hv + n * 512 + ((ch0 * 2) ^ ((n & 7) << 4))) = px;
        }
    }
    __syncthreads();

    f32x4 av[2] = {zero4, zero4};
    f32x4 ar[2][2];
    ar[0][0] = zero4; ar[0][1] = zero4; ar[1][0] = zero4; ar[1][1] = zero4;
    for (int ks = 0; ks < 8; ++ks) {
        f16x8 bh[2];
#pragma unroll
        for (int nt = 0; nt < 2; ++nt) {
            const int n = nt * 16 + li;
            bh[nt] = *(const f16x8*)(hv + n * 512 + ((ks * 64 + g * 16) ^ ((n & 7) << 4)));
        }
        const f16x8 afv = *(const f16x8*)(Wvvh + (size_t)(w * 16 + li) * 256 + ks * 32 + g * 8);
        av[0] = mfma16(afv, bh[0], av[0]);
        av[1] = mfma16(afv, bh[1], av[1]);
#pragma unroll
        for (int rt = 0; rt < 2; ++rt) {
            const f16x8 afr = *(const f16x8*)(Wresh + (size_t)((w * 2 + rt) * 16 + li) * 256 + ks * 32 + g * 8);
            ar[rt][0] = mfma16(afr, bh[0], ar[rt][0]);
            ar[rt][1] = mfma16(afr, bh[1], ar[rt][1]);
        }
    }
    {
        const int ch0 = w * 16 + g * 4;
        const float4 bb = *(const float4*)(bvv + ch0);
#pragma unroll
        for (int nt = 0; nt < 2; ++nt) {
            const int n = nt * 16 + li;
            ushort4 pk;
            pk.x = f2bfu(av[nt][0] + bb.x);
            pk.y = f2bfu(av[nt][1] + bb.y);
            pk.z = f2bfu(av[nt][2] + bb.z);
            pk.w = f2bfu(av[nt][3] + bb.w);
            *(ushort4*)((char*)vf_ws + (((size_t)b * NN + n0 + n) * DD + ch0) * 2) = pk;
        }
    }
#pragma unroll
    for (int rt = 0; rt < 2; ++rt) {
        const int ch0 = (w * 2 + rt) * 16 + g * 4;
        const float4 bb = *(const float4*)(bres + ch0);
#pragma unroll
        for (int nt = 0; nt < 2; ++nt) {
            const int n = nt * 16 + li;
            ushort4 pk;
            pk.x = f2bfu(ar[rt][nt][0] + bb.x);
            pk.y = f2bfu(ar[rt][nt][1] + bb.y);
            pk.z = f2bfu(ar[rt][nt][2] + bb.z);
            pk.w = f2bfu(ar[rt][nt][3] + bb.w);
            *(ushort4*)((char*)resid_ws + (((size_t)b * NN + n0 + n) * COUTN + ch0) * 2) = pk;
        }
    }
}

// ---------------------------------------------------------------------------
// Kernel 4 (fused): 16 n's per block, 16 waves (1024 threads).
// Round 11: NPB 8->16 (halve barriers per point again — round 8's identical
// consolidation gave -22%); 1 block/CU at ~137 KB LDS, same 16 resident
// waves. Phase D gather vectorized to 16B chunks (swizzle is 16B-closed ->
// chunked stores cover identical bytes; math bit-identical).
// r320 = n_local*20 + k. Wave split: C/GEMM1 use (m4 = w&3) x (nh = w>>2 & 3,
// 5 nt each of 20); GEMM2 wave = (cq = w&7 cr-tile) x (nhf = w>>3 nt-half,
// acc2[10]); conv_end wave = (ot = w&7 o-tile) x (ntile = w>>3).
// LDS pool (122880 B) by liveness:
//   @0     : ph16 [320][64] swz (B,C) -> S16 (D, GEMM1)      \ L16T [320]
//   @40960 : peh [320][64] swz (C,D) -> Hl [320][64] (loop)  / [128cr] 80KB
//   @81920 : V16 [320][64] swz (D -> aggregate)
// ---------------------------------------------------------------------------
__global__ __launch_bounds__(1024, 1) void attn_fused(
    const float* __restrict__ posT, const u16* __restrict__ idx_ws,
    const bf16* __restrict__ kf_ws, const bf16* __restrict__ qf_ws,
    const bf16* __restrict__ uf_ws, const bf16* __restrict__ vf_ws,
    const bf16* __restrict__ resid_ws,
    const float* __restrict__ Wp1, const float* __restrict__ bp1,
    const float* __restrict__ gp1, const float* __restrict__ betap1,
    const f16* __restrict__ Wp2h, const float* __restrict__ bp2,
    const f16* __restrict__ Wa1h, const float* __restrict__ A1s,
    const float* __restrict__ A1b, const f16* __restrict__ Wth,
    const f16* __restrict__ Wendh, const float* __restrict__ bend,
    float* __restrict__ out) {
    __shared__ __align__(16) char pool[122880];
    f16*  ph16 = (f16*)(pool);
    f16*  S16  = (f16*)(pool);            // overlays ph16 (dead after C)
    f16*  L16T = (f16*)(pool);            // 80KB: overlays S16+Hl (after loop)
    f16*  peh  = (f16*)(pool + 40960);
    char* Hl   = pool + 40960;            // overlays peh (dead after D)
    f16*  V16  = (f16*)(pool + 81920);
    __shared__ __align__(16) f16 aggf[32 * 64];   // [nr][c] swizzled
    __shared__ int   nidx[NPB * KK];              // 320
    __shared__ float prel[NPB * KK][3];
    __shared__ float qcol[NPB][64], ucol[NPB][64];

    const int b  = blockIdx.x >> 7;           // NN/16 = 128 blocks per batch
    const int n0 = (blockIdx.x & 127) << 4;
    const int t = threadIdx.x;
    const int w = t >> 6, l = t & 63, g = l >> 4, li = l & 15;
    const int m4 = w & 3, nh = (w >> 2) & 3;
    const int cq = w & 7, nhf = w >> 3;
    const size_t row0 = (size_t)b * NN + n0;
    const f32x4 zero4 = {0.f, 0.f, 0.f, 0.f};

    if (t < NPB * KK) nidx[t] = (int)idx_ws[row0 * KK + t];
    __syncthreads();

    // A: per-n q/u columns + prel (1024 threads = 16 n x 64 c exactly)
    {
        const int n = t >> 6, c = t & 63;
        qcol[n][c] = bf2f(qf_ws[(row0 + n) * DD + c]);
        ucol[n][c] = bf2f(uf_ws[(row0 + n) * DD + c]);
    }
    if (t < 960) {
        const int r = t / 3, d = t - r * 3;
        const int n = r / KK;
        prel[r][d] = posT[(row0 + n) * 3 + d] - posT[((size_t)b * NN + nidx[r]) * 3 + d];
    }
    __syncthreads();

    // B: pos_mlp l1 (3->64, BN, ReLU) -> ph16 packed+swizzled
    for (int u = t; u < 320 * 32; u += 1024) {
        const int r = u >> 5, c0 = (u & 31) << 1;
        float a0 = Wp1[c0 * 3 + 0] * prel[r][0] + Wp1[c0 * 3 + 1] * prel[r][1]
                 + Wp1[c0 * 3 + 2] * prel[r][2] + bp1[c0];
        float a1 = Wp1[c0 * 3 + 3] * prel[r][0] + Wp1[c0 * 3 + 4] * prel[r][1]
                 + Wp1[c0 * 3 + 5] * prel[r][2] + bp1[c0 + 1];
        a0 = gp1[c0] * a0 * BN_INV + betap1[c0];
        a1 = gp1[c0 + 1] * a1 * BN_INV + betap1[c0 + 1];
        h2 pr; pr.x = (f16)fmaxf(a0, 0.f); pr.y = (f16)fmaxf(a1, 0.f);
        *(unsigned*)((char*)ph16 + (r * 128 + ((c0 * 2) ^ ((r & 7) << 4)))) =
            __builtin_bit_cast(unsigned, pr);
    }
    __syncthreads();

    // C: pos_mlp l2 via MFMA (M=64 co, N=320 nk, K=64) -> peh[nk][co]+bp2
    {
        f32x4 d[5];
#pragma unroll
        for (int j = 0; j < 5; ++j) d[j] = zero4;
#pragma unroll
        for (int ks = 0; ks < 2; ++ks) {
            const f16x8 af = *(const f16x8*)(Wp2h + (m4 * 16 + li) * 64 + ks * 32 + g * 8);
#pragma unroll
            for (int j = 0; j < 5; ++j) {
                const int r = (nh * 5 + j) * 16 + li;
                const f16x8 bf = *(const f16x8*)((const char*)ph16 +
                                  (r * 128 + ((ks * 64 + g * 16) ^ ((r & 7) << 4))));
                d[j] = mfma16(af, bf, d[j]);
            }
        }
        const int ch0 = m4 * 16 + g * 4;
        const float4 b4 = *(const float4*)(bp2 + ch0);
#pragma unroll
        for (int j = 0; j < 5; ++j) {
            const int r = (nh * 5 + j) * 16 + li;
            f16x4 pk;
            pk.x = (f16)(d[j][0] + b4.x);
            pk.y = (f16)(d[j][1] + b4.y);
            pk.z = (f16)(d[j][2] + b4.z);
            pk.w = (f16)(d[j][3] + b4.w);
            *(f16x4*)((char*)peh + (r * 128 + ((ch0 * 2) ^ ((r & 7) << 4)))) = pk;
        }
    }
    __syncthreads();

    // D: gather + combine, 16B-vectorized (8 channels/chunk) -> S16, V16
    for (int u = t; u < 320 * 8; u += 1024) {
        const int r = u >> 3, cg = (u & 7) << 3;
        const int n = r / KK;
        const size_t nb = (((size_t)b * NN + nidx[r]) * DD + cg) * 2;
        const uint4 kq = *(const uint4*)((const char*)kf_ws + nb);
        const uint4 uq = *(const uint4*)((const char*)uf_ws + nb);
        const uint4 vq = *(const uint4*)((const char*)vf_ws + nb);
        const int sw = (cg * 2) ^ ((r & 7) << 4);
        const uint4 pw = *(const uint4*)((const char*)peh + (r * 128 + sw));
        uint4 sres, vres;
#define PROC(comp, off) { \
        const float k0 = lo2f(kq.comp), k1 = hi2f(kq.comp); \
        const float u0 = lo2f(uq.comp), u1 = hi2f(uq.comp); \
        const float v0 = lo2f(vq.comp), v1 = hi2f(vq.comp); \
        const h2 pp = __builtin_bit_cast(h2, pw.comp); \
        const float add0 = ucol[n][cg + off]     + (float)pp.x; \
        const float add1 = ucol[n][cg + off + 1] + (float)pp.y; \
        h2 s; s.x = (f16)(-(k0 + u0) + qcol[n][cg + off] + add0); \
              s.y = (f16)(-(k1 + u1) + qcol[n][cg + off + 1] + add1); \
        h2 v; v.x = (f16)(v0 - u0 + add0); v.y = (f16)(v1 - u1 + add1); \
        sres.comp = __builtin_bit_cast(unsigned, s); \
        vres.comp = __builtin_bit_cast(unsigned, v); }
        PROC(x, 0) PROC(y, 2) PROC(z, 4) PROC(w, 6)
#undef PROC
        *(uint4*)((char*)S16 + (r * 128 + sw)) = sres;
        *(uint4*)((char*)V16 + (r * 128 + sw)) = vres;
    }
    __syncthreads();

    // GEMM loop: 4 chunks of 64 H-rows.
    f32x4 acc2[10];
#pragma unroll
    for (int j = 0; j < 10; ++j) acc2[j] = zero4;

    for (int c4 = 0; c4 < 4; ++c4) {
        const int hrb = c4 * 64 + m4 * 16;
        f32x4 d1[5];
#pragma unroll
        for (int j = 0; j < 5; ++j) d1[j] = zero4;
#pragma unroll
        for (int ks = 0; ks < 2; ++ks) {
            const f16x8 af = *(const f16x8*)(Wa1h + (hrb + li) * 64 + ks * 32 + g * 8);
#pragma unroll
            for (int j = 0; j < 5; ++j) {
                const int r = (nh * 5 + j) * 16 + li;
                const f16x8 sfv = *(const f16x8*)((const char*)S16 +
                                   (r * 128 + ((ks * 64 + g * 16) ^ ((r & 7) << 4))));
                d1[j] = mfma16(af, sfv, d1[j]);
            }
        }
        const float4 as4 = *(const float4*)(A1s + hrb + g * 4);
        const float4 ab4 = *(const float4*)(A1b + hrb + g * 4);
        __syncthreads();   // prior chunk's GEMM2 (and c4=0: phase D) done
#pragma unroll
        for (int j = 0; j < 5; ++j) {
            const int col = (nh * 5 + j) * 16 + li;
            const int ch0 = m4 * 16 + g * 4;   // chunk-local H row
            f16x4 pk;
            pk.x = (f16)fmaxf(as4.x * d1[j][0] + ab4.x, 0.f);
            pk.y = (f16)fmaxf(as4.y * d1[j][1] + ab4.y, 0.f);
            pk.z = (f16)fmaxf(as4.z * d1[j][2] + ab4.z, 0.f);
            pk.w = (f16)fmaxf(as4.w * d1[j][3] + ab4.w, 0.f);
            *(f16x4*)(Hl + col * 128 + ((ch0 * 2) ^ ((col & 7) << 4))) = pk;
        }
        __syncthreads();
#pragma unroll
        for (int ks2 = 0; ks2 < 2; ++ks2) {
            const f16x8 bf = *(const f16x8*)(Wth + (size_t)(cq * 16 + li) * AHH + c4 * 64 + ks2 * 32 + g * 8);
#pragma unroll
            for (int j = 0; j < 10; ++j) {
                const int col = (nhf * 10 + j) * 16 + li;
                const f16x8 ha = *(const f16x8*)(Hl + col * 128 + ((ks2 * 64 + g * 16) ^ ((col & 7) << 4)));
                acc2[j] = mfma16(ha, bf, acc2[j]);
            }
        }
    }
    __syncthreads();   // Hl/S16 reads done before L16T overlays both

    // logits L16T[row=nk][col=cr], XOR((row&3)<<5)
#pragma unroll
    for (int j = 0; j < 10; ++j) {
        const f32x4 d = acc2[j];
#pragma unroll
        for (int jj = 0; jj < 4; ++jj) {
            const int row = (nhf * 10 + j) * 16 + g * 4 + jj;
            *(f16*)((char*)L16T + (row * 256 + (((cq * 16 + li) * 2) ^ ((row & 3) << 5)))) =
                (f16)d[jj];
        }
    }
    __syncthreads();

    // softmax over k + aggregate with V16 -> aggf[nr][c] f16 swizzled
    {
        const int cr = t & 127, c = cr >> 1, rr = cr & 1;
        const int nbase = (t >> 7) * 2;
        for (int p = 0; p < 2; ++p) {
            const int n = nbase + p;
            float lv[20];
#pragma unroll
            for (int k = 0; k < 20; ++k) {
                const int row = n * KK + k;
                lv[k] = (float)*(const f16*)((const char*)L16T +
                          (row * 256 + ((cr * 2) ^ ((row & 3) << 5))));
            }
            float m = lv[0];
#pragma unroll
            for (int k = 1; k < 20; ++k) m = fmaxf(m, lv[k]);
            float s = 0.f, a = 0.f;
#pragma unroll
            for (int k = 0; k < 20; ++k) {
                const float e = __expf(lv[k] - m);
                s += e;
                const int r = n * KK + k;
                const float vv = (float)*(const f16*)((const char*)V16 +
                                   (r * 128 + ((c * 2) ^ ((r & 7) << 4))));
                a += e * vv;
            }
            const int arow = n * 2 + rr;
            *(f16*)((char*)aggf + (arow * 128 + ((c * 2) ^ ((arow & 7) << 4)))) = (f16)(a / s);
        }
    }
    __syncthreads();

    // conv_end via MFMA: wave = (ot = w&7 o-tile) x (ntile = w>>3 n-tile).
    // D col li -> output offset 2n0 + ntile*16 + li (64B-coalesced).
    {
        const int ot = w & 7, ntile = w >> 3;
        const int nr = ntile * 16 + li;
        f32x4 dc = zero4;
#pragma unroll
        for (int ks = 0; ks < 2; ++ks) {
            const f16x8 af = *(const f16x8*)(Wendh + (size_t)(ot * 16 + li) * 64 + ks * 32 + g * 8);
            const f16x8 bfr = *(const f16x8*)((const char*)aggf +
                               (nr * 128 + (((ks * 32 + g * 8) * 2) ^ ((nr & 7) << 4))));
            dc = mfma16(af, bfr, dc);
        }
        const int nloc = nr >> 1;
#pragma unroll
        for (int j = 0; j < 4; ++j) {
            const int o = ot * 16 + g * 4 + j;
            const float rv = bf2f(resid_ws[(row0 + nloc) * COUTN + o]);
            out[(size_t)b * COUTN * (NN * UPF) + (size_t)o * (NN * UPF) + 2 * n0 + nr] =
                dc[j] + bend[o] + rv;
        }
    }
}

extern "C" void kernel_launch(void* const* d_in, const int* in_sizes, int n_in,
                              void* d_out, int out_size, void* d_ws, size_t ws_size,
                              hipStream_t stream) {
    const float* pos        = (const float*)d_in[0];
    const float* key_feat   = (const float*)d_in[1];
    const float* query_feat = (const float*)d_in[2];
    const float* upfeat     = (const float*)d_in[3];
    const float* Wv1 = (const float*)d_in[4];
    const float* bv1 = (const float*)d_in[5];
    const float* Wv2 = (const float*)d_in[6];
    const float* bv2 = (const float*)d_in[7];
    const float* Wvs = (const float*)d_in[8];
    const float* bvs = (const float*)d_in[9];
    const float* Wk  = (const float*)d_in[10];
    const float* bk  = (const float*)d_in[11];
    const float* Wq  = (const float*)d_in[12];
    const float* bq  = (const float*)d_in[13];
    const float* Wvv = (const float*)d_in[14];
    const float* bvv = (const float*)d_in[15];
    const float* Wu  = (const float*)d_in[16];
    const float* bu  = (const float*)d_in[17];
    const float* Wp1 = (const float*)d_in[18];
    const float* bp1 = (const float*)d_in[19];
    const float* gp1 = (const float*)d_in[20];
    const float* betap1 = (const float*)d_in[21];
    const float* Wp2 = (const float*)d_in[22];
    const float* bp2 = (const float*)d_in[23];
    const float* Wa1 = (const float*)d_in[24];
    const float* ba1 = (const float*)d_in[25];
    const float* ga1 = (const float*)d_in[26];
    const float* betaa1 = (const float*)d_in[27];
    const float* Wt   = (const float*)d_in[28];
    const float* bt   = (const float*)d_in[29];
    const float* Wend = (const float*)d_in[30];
    const float* bend = (const float*)d_in[31];
    const float* Wres = (const float*)d_in[32];
    const float* bres = (const float*)d_in[33];
    float* out = (float*)d_out;
    (void)out_size; (void)bt;   // bt cancels in softmax (uniform over k)

    const bool sizes_ok = (n_in >= 34)
        && (in_sizes[0] == BB * 3 * NN)
        && (in_sizes[1] == BB * CIN * NN)
        && (in_sizes[4] == CIN * 2 * CIN)
        && (in_sizes[28] == AHH * DD * UPF)
        && (in_sizes[32] == COUTN * CIN);

    size_t off = 0;
    auto take = [&](size_t bytes) { size_t o = off; off = (off + bytes + 255) & ~(size_t)255; return o; };
    const size_t off_posT  = take((size_t)BB * NN * 3 * sizeof(float));
    const size_t off_idx   = take((size_t)BB * NN * KK * sizeof(u16));
    const size_t off_vf    = take((size_t)BB * NN * DD * sizeof(bf16));
    const size_t off_kf    = take((size_t)BB * NN * DD * sizeof(bf16));
    const size_t off_qf    = take((size_t)BB * NN * DD * sizeof(bf16));
    const size_t off_uf    = take((size_t)BB * NN * DD * sizeof(bf16));
    const size_t off_resid = take((size_t)BB * NN * COUTN * sizeof(bf16));
    const size_t off_wa1h  = take((size_t)AHH * DD * sizeof(f16));
    const size_t off_wp2h  = take((size_t)PHH * DD * sizeof(f16));
    const size_t off_wth   = take((size_t)COUTN * AHH * sizeof(f16));
    const size_t off_a1s   = take((size_t)AHH * sizeof(float));
    const size_t off_a1b   = take((size_t)AHH * sizeof(float));
    const size_t off_wendh = take((size_t)COUTN * DD * sizeof(f16));
    const size_t off_wv1h  = take((size_t)CIN * 2 * CIN * sizeof(f16));
    const size_t off_wv2h  = take((size_t)CIN * CIN * sizeof(f16));
    const size_t off_wvsh  = take((size_t)CIN * 2 * CIN * sizeof(f16));
    const size_t off_wvvh  = take((size_t)DD * CIN * sizeof(f16));
    const size_t off_wresh = take((size_t)COUTN * CIN * sizeof(f16));
    const size_t off_wkh   = take((size_t)DD * CIN * sizeof(f16));
    const size_t off_wqh   = take((size_t)DD * CIN * sizeof(f16));
    const size_t off_wuh   = take((size_t)DD * CIN * sizeof(f16));
    const size_t off_xkq   = take((size_t)BB * NN * 512 * sizeof(f16));
    const size_t off_xu    = take((size_t)BB * NN * 256 * sizeof(f16));
    const size_t NEED = off;

    if (!sizes_ok) return;
    if (ws_size < NEED) {
        sentinel_kernel<<<1, 64, 0, stream>>>(out);
        return;
    }

    char* ws = (char*)d_ws;
    float* posT_ws  = (float*)(ws + off_posT);
    u16*   idx_ws   = (u16*)(ws + off_idx);
    bf16*  vf_ws    = (bf16*)(ws + off_vf);
    bf16*  kf_ws    = (bf16*)(ws + off_kf);
    bf16*  qf_ws    = (bf16*)(ws + off_qf);
    bf16*  uf_ws    = (bf16*)(ws + off_uf);
    bf16*  resid_ws = (bf16*)(ws + off_resid);
    f16*   Wa1h_ws  = (f16*)(ws + off_wa1h);
    f16*   Wp2h_ws  = (f16*)(ws + off_wp2h);
    f16*   Wth_ws   = (f16*)(ws + off_wth);
    float* A1s_ws   = (float*)(ws + off_a1s);
    float* A1b_ws   = (float*)(ws + off_a1b);
    f16*   Wendh_ws = (f16*)(ws + off_wendh);
    f16*   Wv1h_ws  = (f16*)(ws + off_wv1h);
    f16*   Wv2h_ws  = (f16*)(ws + off_wv2h);
    f16*   Wvsh_ws  = (f16*)(ws + off_wvsh);
    f16*   Wvvh_ws  = (f16*)(ws + off_wvvh);
    f16*   Wresh_ws = (f16*)(ws + off_wresh);
    f16*   Wkh_ws   = (f16*)(ws + off_wkh);
    f16*   Wqh_ws   = (f16*)(ws + off_wqh);
    f16*   Wuh_ws   = (f16*)(ws + off_wuh);
    f16*   xkqT_ws  = (f16*)(ws + off_xkq);
    f16*   xuT_ws   = (f16*)(ws + off_xu);

    prep_kernel<<<(CIN * 2 * CIN + 255) / 256, 256, 0, stream>>>(
        Wa1, Wp2, Wend, Wt, Wv1, Wv2, Wvs, Wvv, Wres, Wk, Wq, Wu,
        ba1, ga1, betaa1,
        Wa1h_ws, Wp2h_ws, Wth_ws, A1s_ws, A1b_ws, Wendh_ws,
        Wv1h_ws, Wv2h_ws, Wvsh_ws, Wvvh_ws, Wresh_ws, Wkh_ws, Wqh_ws, Wuh_ws);
    xpose_kernel<<<dim3(BB * (NN / 64), 12), 256, 0, stream>>>(
        key_feat, query_feat, upfeat, xkqT_ws, xuT_ws);
    knn_kernel<<<BB * NN, 256, 0, stream>>>(pos, idx_ws, posT_ws);
    value_mfma<<<BB * (NN / 32), 256, 0, stream>>>(xkqT_ws, xuT_ws,
        Wv1h_ws, bv1, Wv2h_ws, bv2, Wvsh_ws, bvs, Wvvh_ws, bvv, Wresh_ws, bres,
        Wkh_ws, bk, Wqh_ws, bq, Wuh_ws, bu,
        vf_ws, resid_ws, kf_ws, qf_ws, uf_ws);
    attn_fused<<<BB * (NN / NPB), 1024, 0, stream>>>(posT_ws, idx_ws,
        kf_ws, qf_ws, uf_ws, vf_ws, resid_ws,
        Wp1, bp1, gp1, betap1, Wp2h_ws, bp2,
        Wa1h_ws, A1s_ws, A1b_ws, Wth_ws, Wendh_ws, bend, out);
}

// Round 12
// 419.450 us; speedup vs baseline: 1.0390x; 1.0390x over previous
//
#include <hip/hip_runtime.h>
#include <hip/hip_bf16.h>
#include <math.h>

#define BB 8
#define NN 2048
#define KK 20
#define UPF 2
#define CIN 256
#define DD 64
#define COUTN 128
#define PHH 64
#define AHH 256
#define BN_INV 0.9999950000374997f   // np.float32(1/sqrt(1+1e-5))
#define NPB 8                        // attn n's per block (8 waves; 16 regressed: 1 blk/CU)

typedef __hip_bfloat16 bf16;
typedef unsigned short u16;
typedef unsigned long long u64;
typedef _Float16 f16;
typedef _Float16 h2   __attribute__((ext_vector_type(2)));
typedef _Float16 f16x4 __attribute__((ext_vector_type(4)));
typedef _Float16 f16x8 __attribute__((ext_vector_type(8)));
typedef float    f32x4 __attribute__((ext_vector_type(4)));

static __device__ __forceinline__ float bf2f(const bf16 v) { return __bfloat162float(v); }
static __device__ __forceinline__ bf16  f2bf(const float v) { return __float2bfloat16(v); }
static __device__ __forceinline__ u16   f2bfu(const float v) {
    return __builtin_bit_cast(u16, __float2bfloat16(v));
}
// exact bf16(bits)->f32
static __device__ __forceinline__ float lo2f(const unsigned v) { return __builtin_bit_cast(float, v << 16); }
static __device__ __forceinline__ float hi2f(const unsigned v) { return __builtin_bit_cast(float, v & 0xFFFF0000u); }

static __device__ __forceinline__ f32x4 mfma16(const f16x8 a, const f16x8 b, const f32x4 c) {
    return __builtin_amdgcn_mfma_f32_16x16x32_f16(a, b, c, 0, 0, 0);
}
// order-preserving float->u32 map: ascending float => ascending unsigned.
static __device__ __forceinline__ unsigned fmap(const float f) {
    unsigned u = __builtin_bit_cast(unsigned, f);
    return (u >> 31) ? ~u : (u | 0x80000000u);
}

__global__ void sentinel_kernel(float* out) {
    if (threadIdx.x == 0 && blockIdx.x == 0) out[0] = 100.0f;
}

// ---------------------------------------------------------------------------
// Kernel 0: weight prep (f16 k-contiguous rows for MFMA; Wth transposed;
// A1s/A1b folded BN; Wendh f16 for the conv_end MFMA).
// ---------------------------------------------------------------------------
__global__ __launch_bounds__(256) void prep_kernel(
    const float* __restrict__ Wa1, const float* __restrict__ Wp2,
    const float* __restrict__ Wend, const float* __restrict__ Wt,
    const float* __restrict__ Wv1, const float* __restrict__ Wv2,
    const float* __restrict__ Wvs, const float* __restrict__ Wvv,
    const float* __restrict__ Wres,
    const float* __restrict__ Wk, const float* __restrict__ Wq,
    const float* __restrict__ Wu,
    const float* __restrict__ ba1, const float* __restrict__ ga1,
    const float* __restrict__ betaa1,
    f16* __restrict__ Wa1h, f16* __restrict__ Wp2h, f16* __restrict__ Wth,
    float* __restrict__ A1s, float* __restrict__ A1b,
    f16* __restrict__ Wendh,
    f16* __restrict__ Wv1h, f16* __restrict__ Wv2h, f16* __restrict__ Wvsh,
    f16* __restrict__ Wvvh, f16* __restrict__ Wresh,
    f16* __restrict__ Wkh, f16* __restrict__ Wqh, f16* __restrict__ Wuh) {
    const int t = blockIdx.x * 256 + threadIdx.x;
    if (t < AHH * DD)        Wa1h[t] = (f16)Wa1[t];
    if (t < PHH * DD)        Wp2h[t] = (f16)Wp2[t];
    if (t < COUTN * AHH)     { int cr = t >> 8, hh = t & 255; Wth[t] = (f16)Wt[hh * COUTN + cr]; }
    if (t < AHH) {
        float gsc = ga1[t] * BN_INV;
        A1s[t] = gsc;
        A1b[t] = gsc * ba1[t] + betaa1[t];
    }
    if (t < COUTN * DD)      Wendh[t] = (f16)Wend[t];
    if (t < CIN * 2 * CIN)   Wv1h[t] = (f16)Wv1[t];
    if (t < CIN * CIN)       Wv2h[t] = (f16)Wv2[t];
    if (t < CIN * 2 * CIN)   Wvsh[t] = (f16)Wvs[t];
    if (t < DD * CIN)        Wvvh[t] = (f16)Wvv[t];
    if (t < COUTN * CIN)     Wresh[t] = (f16)Wres[t];
    if (t < DD * CIN)        Wkh[t]  = (f16)Wk[t];
    if (t < DD * CIN)        Wqh[t]  = (f16)Wq[t];
    if (t < DD * CIN)        Wuh[t]  = (f16)Wu[t];
}

// ---------------------------------------------------------------------------
// Kernel 0b: transpose key/query/upfeat (B,C,N) fp32 -> point-major f16.
// ---------------------------------------------------------------------------
__global__ __launch_bounds__(256) void xpose_kernel(
    const float* __restrict__ key_feat, const float* __restrict__ query_feat,
    const float* __restrict__ upfeat,
    f16* __restrict__ xkqT, f16* __restrict__ xuT) {
    __shared__ float tile[64][65];
    const int b  = blockIdx.x >> 5;
    const int n0 = (blockIdx.x & 31) << 6;
    const int y  = blockIdx.y;
    const int src = y >> 2;
    const int ct  = (y & 3) << 6;
    const int t = threadIdx.x;
    const float* xin = (src == 0) ? key_feat : (src == 1) ? query_feat : upfeat;
    f16* dst; int CT, cb;
    if (src < 2) { dst = xkqT; CT = 512; cb = src * 256 + ct; }
    else         { dst = xuT;  CT = 256; cb = ct; }
    for (int u = t; u < 64 * 64; u += 256) {
        const int c = u >> 6, j = u & 63;
        tile[c][j] = xin[((size_t)b * CIN + ct + c) * NN + n0 + j];
    }
    __syncthreads();
    for (int u = t; u < 64 * 32; u += 256) {
        const int n = u >> 5, c0 = (u & 31) << 1;
        h2 pr; pr.x = (f16)tile[c0][n]; pr.y = (f16)tile[c0 + 1][n];
        ((unsigned*)dst)[(((size_t)b * NN + n0 + n) * CT + cb + c0) >> 1] =
            __builtin_bit_cast(unsigned, pr);
    }
}

// ---------------------------------------------------------------------------
// Kernel 1: KNN — block per query, adaptive single-histogram select
// (verified round 9; fallback = verified round-5 radix).
// ---------------------------------------------------------------------------
__global__ __launch_bounds__(256) void knn_kernel(const float* __restrict__ pos,
                                                  u16* __restrict__ idx_out,
                                                  float* __restrict__ posT) {
    __shared__ float dist[NN];
    __shared__ int   hist[512];
    __shared__ unsigned rmin[4], rmax[4];
    __shared__ u64   cbuf[64];
    __shared__ float q[3];
    __shared__ unsigned minkS;
    __shared__ int   shiftS, jstarS, cntS;
    __shared__ u64   ltbuf[KK];
    __shared__ int   tiebuf[64];
    __shared__ int   ri[4];
    __shared__ unsigned prefS;
    __shared__ int   knS, cnt_lt, cnt_eq;

    const int b = blockIdx.x / NN;
    const int n = blockIdx.x % NN;
    const int t = threadIdx.x;
    const float* pb = pos + (size_t)b * 3 * NN;
    const size_t rowKK = ((size_t)b * NN + n) * KK;

    if (t < 3) {
        float v = pb[(size_t)t * NN + n];
        q[t] = v;
        posT[((size_t)b * NN + n) * 3 + t] = v;
    }
    if (t == 0) { prefS = 0u; knS = KK; cnt_lt = 0; cnt_eq = 0; cntS = 0; jstarS = 0; }
    __syncthreads();
    const float qx = q[0], qy = q[1], qz = q[2];
    const float sqq = __fadd_rn(__fadd_rn(__fmul_rn(qx, qx), __fmul_rn(qy, qy)), __fmul_rn(qz, qz));
    unsigned kmin = 0xFFFFFFFFu, kmax = 0u;
    for (int m = t; m < NN; m += 256) {
        float px = pb[m];
        float py = pb[NN + m];
        float pz = pb[2 * NN + m];
        float sqm = __fadd_rn(__fadd_rn(__fmul_rn(px, px), __fmul_rn(py, py)), __fmul_rn(pz, pz));
        float dt  = __fadd_rn(__fadd_rn(__fmul_rn(qx, px), __fmul_rn(qy, py)), __fmul_rn(qz, pz));
        const float d = __fsub_rn(__fadd_rn(sqq, sqm), __fmul_rn(2.0f, dt));
        dist[m] = d;
        const unsigned key = fmap(d);
        kmin = min(kmin, key);
        kmax = max(kmax, key);
    }
#pragma unroll
    for (int off = 32; off > 0; off >>= 1) {
        kmin = min(kmin, (unsigned)__shfl_down((int)kmin, off, 64));
        kmax = max(kmax, (unsigned)__shfl_down((int)kmax, off, 64));
    }
    if ((t & 63) == 0) { rmin[t >> 6] = kmin; rmax[t >> 6] = kmax; }
    hist[t] = 0; hist[256 + t] = 0;
    __syncthreads();
    if (t == 0) {
        const unsigned mn = min(min(rmin[0], rmin[1]), min(rmin[2], rmin[3]));
        const unsigned mx = max(max(rmax[0], rmax[1]), max(rmax[2], rmax[3]));
        const unsigned range = mx - mn;
        minkS  = mn;
        shiftS = (range >= 256u) ? (24 - __clz((int)range)) : 0;
    }
    __syncthreads();
    const unsigned mink = minkS;
    const int sh = shiftS;

    for (int m = t; m < NN; m += 256) {
        const unsigned bin = (fmap(dist[m]) - mink) >> sh;
        atomicAdd(&hist[((unsigned)(t & 1) << 8) | bin], 1);
    }
    __syncthreads();
    if (t < 64) {
        const int h0  = hist[4 * t + 0] + hist[256 + 4 * t + 0];
        const int h1  = hist[4 * t + 1] + hist[256 + 4 * t + 1];
        const int h2v = hist[4 * t + 2] + hist[256 + 4 * t + 2];
        const int h3  = hist[4 * t + 3] + hist[256 + 4 * t + 3];
        const int lsum = h0 + h1 + h2v + h3;
        int incl = lsum;
#pragma unroll
        for (int off = 1; off < 64; off <<= 1) {
            int v = __shfl_up(incl, off, 64);
            if (t >= off) incl += v;
        }
        const int excl = incl - lsum;
        if (excl < KK && excl + lsum >= KK) {
            int bsel;
            if      (excl + h0 >= KK)            bsel = 0;
            else if (excl + h0 + h1 >= KK)       bsel = 1;
            else if (excl + h0 + h1 + h2v >= KK) bsel = 2;
            else                                 bsel = 3;
            jstarS = 4 * t + bsel;
        }
    }
    __syncthreads();
    const unsigned jstar = (unsigned)jstarS;

    for (int m = t; m < NN; m += 256) {
        const unsigned key = fmap(dist[m]);
        if (((key - mink) >> sh) <= jstar) {
            const int p = atomicAdd(&cntS, 1);
            if (p < 64) cbuf[p] = ((u64)key << 32) | (unsigned)m;
        }
    }
    __syncthreads();
    const int total = cntS;

    if (total <= 64) {
        if (t < 64) {
            u64 v = (t < total) ? cbuf[t] : 0xFFFFFFFFFFFFFFFFull;
            int rank = 0;
#pragma unroll 16
            for (int j = 0; j < 64; ++j) {
                const u64 o = (u64)__shfl((long long)v, j, 64);
                if (o < v) ++rank;
            }
            if (t < total && rank < KK) idx_out[rowKK + rank] = (u16)(v & 0xFFFFu);
        }
        return;
    }

    // ---- fallback: verified 4-pass radix select ----
    for (int pass = 0; pass < 4; ++pass) {
        const int shift = 24 - 8 * pass;
        const unsigned pm = (pass == 0) ? 0u : (0xFFFFFFFFu << (32 - 8 * pass));
        hist[t] = 0;
        __syncthreads();
        const unsigned pref = prefS;
        const int kn = knS;
        for (int m = t; m < NN; m += 256) {
            unsigned key = fmap(dist[m]);
            if ((key & pm) == pref)
                atomicAdd(&hist[(key >> shift) & 255], 1);
        }
        __syncthreads();
        if (t < 64) {
            const int h0 = hist[4 * t + 0], h1 = hist[4 * t + 1];
            const int h2v = hist[4 * t + 2], h3 = hist[4 * t + 3];
            const int lsum = h0 + h1 + h2v + h3;
            int incl = lsum;
#pragma unroll
            for (int off = 1; off < 64; off <<= 1) {
                int v = __shfl_up(incl, off, 64);
                if (t >= off) incl += v;
            }
            const int excl = incl - lsum;
            if (excl < kn && excl + lsum >= kn) {
                int bsel, cb;
                if      (excl + h0 >= kn)            { bsel = 0; cb = excl; }
                else if (excl + h0 + h1 >= kn)       { bsel = 1; cb = excl + h0; }
                else if (excl + h0 + h1 + h2v >= kn) { bsel = 2; cb = excl + h0 + h1; }
                else                                 { bsel = 3; cb = excl + h0 + h1 + h2v; }
                knS = kn - cb;
                prefS = pref | ((unsigned)(4 * t + bsel) << shift);
            }
        }
        __syncthreads();
    }

    const unsigned T = prefS;
    for (int m = t; m < NN; m += 256) {
        unsigned key = fmap(dist[m]);
        if (key < T) {
            int p = atomicAdd(&cnt_lt, 1);
            ltbuf[p] = ((u64)key << 32) | (unsigned)m;
        } else if (key == T) {
            int p = atomicAdd(&cnt_eq, 1);
            if (p < 64) tiebuf[p] = m;
        }
    }
    __syncthreads();
    const int nlt = cnt_lt, neq_need = knS, ceq = cnt_eq;

    if (t < 64) {
        u64 v = (t < nlt) ? ltbuf[t] : 0xFFFFFFFFFFFFFFFFull;
        int rank = 0;
#pragma unroll
        for (int j = 0; j < KK; ++j) {
            const u64 o = (u64)__shfl((long long)v, j, 64);
            if (o < v) ++rank;
        }
        if (t < nlt) idx_out[rowKK + rank] = (u16)(v & 0xFFFFu);
    }
    if (ceq <= 64) {
        if (t < 64) {
            int ti = (t < ceq) ? tiebuf[t] : 0x7FFFFFFF;
            int rk = 0;
            for (int j = 0; j < 64; ++j) {
                const int o = __shfl(ti, j, 64);
                if (o < ti) ++rk;
            }
            if (t < ceq && rk < neq_need) idx_out[rowKK + nlt + rk] = (u16)ti;
        }
    } else {
        for (int iter = 0; iter < neq_need; ++iter) {
            int bi = NN;
            for (int m = t; m < NN; m += 256)
                if (fmap(dist[m]) == T && m < bi) bi = m;
            for (int off = 32; off > 0; off >>= 1) {
                int i2 = __shfl_down(bi, off, 64);
                bi = min(bi, i2);
            }
            if ((t & 63) == 0) ri[t >> 6] = bi;
            __syncthreads();
            if (t == 0) {
                int i0 = min(min(ri[0], ri[1]), min(ri[2], ri[3]));
                idx_out[rowKK + nlt + iter] = (u16)i0;
                dist[i0] = 3.4e38f;
            }
            __syncthreads();
        }
    }
}

// ---------------------------------------------------------------------------
// Kernel 2 (MFMA): value path + fused kf/qf/uf projections (verified r10).
// ---------------------------------------------------------------------------
__global__ __launch_bounds__(256) void value_mfma(
    const f16* __restrict__ xkqT, const f16* __restrict__ xuT,
    const f16* __restrict__ Wv1h, const float* __restrict__ bv1,
    const f16* __restrict__ Wv2h, const float* __restrict__ bv2,
    const f16* __restrict__ Wvsh, const float* __restrict__ bvs,
    const f16* __restrict__ Wvvh, const float* __restrict__ bvv,
    const f16* __restrict__ Wresh, const float* __restrict__ bres,
    const f16* __restrict__ Wkh, const float* __restrict__ bk,
    const f16* __restrict__ Wqh, const float* __restrict__ bq,
    const f16* __restrict__ Wuh, const float* __restrict__ bu,
    bf16* __restrict__ vf_ws, bf16* __restrict__ resid_ws,
    bf16* __restrict__ kf, bf16* __restrict__ qf, bf16* __restrict__ uf) {
    __shared__ __align__(16) char hv[32 * 512];
    const int b  = blockIdx.x >> 6;
    const int n0 = (blockIdx.x & 63) << 5;
    const int t = threadIdx.x;
    const int w = t >> 6, l = t & 63, g = l >> 4, li = l & 15;
    const f16* xb = xkqT + ((size_t)b * NN + n0) * 512;
    const f32x4 zero4 = {0.f, 0.f, 0.f, 0.f};

    f32x4 a1[4][2];
    f32x4 ak[2] = {zero4, zero4}, aq[2] = {zero4, zero4};
#pragma unroll
    for (int mt = 0; mt < 4; ++mt) { a1[mt][0] = zero4; a1[mt][1] = zero4; }
    for (int ks = 0; ks < 16; ++ks) {
        f16x8 bx0 = *(const f16x8*)(xb + (size_t)li * 512 + ks * 32 + g * 8);
        f16x8 bx1 = *(const f16x8*)(xb + (size_t)(16 + li) * 512 + ks * 32 + g * 8);
#pragma unroll
        for (int mt = 0; mt < 4; ++mt) {
            const f16x8 af = *(const f16x8*)(Wv1h + (size_t)(w * 64 + mt * 16 + li) * 512 + ks * 32 + g * 8);
            a1[mt][0] = mfma16(af, bx0, a1[mt][0]);
            a1[mt][1] = mfma16(af, bx1, a1[mt][1]);
        }
        if (ks < 8) {
            const f16x8 afk = *(const f16x8*)(Wkh + (size_t)(w * 16 + li) * 256 + ks * 32 + g * 8);
            ak[0] = mfma16(afk, bx0, ak[0]);
            ak[1] = mfma16(afk, bx1, ak[1]);
        } else {
            const f16x8 afq = *(const f16x8*)(Wqh + (size_t)(w * 16 + li) * 256 + (ks - 8) * 32 + g * 8);
            aq[0] = mfma16(afq, bx0, aq[0]);
            aq[1] = mfma16(afq, bx1, aq[1]);
        }
    }
    f32x4 au[2] = {zero4, zero4};
    {
        const f16* xub = xuT + ((size_t)b * NN + n0) * 256;
        for (int ks = 0; ks < 8; ++ks) {
            f16x8 bu0 = *(const f16x8*)(xub + (size_t)li * 256 + ks * 32 + g * 8);
            f16x8 bu1 = *(const f16x8*)(xub + (size_t)(16 + li) * 256 + ks * 32 + g * 8);
            const f16x8 af = *(const f16x8*)(Wuh + (size_t)(w * 16 + li) * 256 + ks * 32 + g * 8);
            au[0] = mfma16(af, bu0, au[0]);
            au[1] = mfma16(af, bu1, au[1]);
        }
    }
#pragma unroll
    for (int mt = 0; mt < 4; ++mt) {
        const int ch0 = w * 64 + mt * 16 + g * 4;
        const float4 b4 = *(const float4*)(bv1 + ch0);
#pragma unroll
        for (int nt = 0; nt < 2; ++nt) {
            const int n = nt * 16 + li;
            f16x4 px;
            px.x = (f16)fmaxf(a1[mt][nt][0] + b4.x, 0.f);
            px.y = (f16)fmaxf(a1[mt][nt][1] + b4.y, 0.f);
            px.z = (f16)fmaxf(a1[mt][nt][2] + b4.z, 0.f);
            px.w = (f16)fmaxf(a1[mt][nt][3] + b4.w, 0.f);
            *(f16x4*)(hv + n * 512 + ((ch0 * 2) ^ ((n & 7) << 4))) = px;
        }
    }
    {
        const int ch0 = w * 16 + g * 4;
        const float4 bk4 = *(const float4*)(bk + ch0);
        const float4 bq4 = *(const float4*)(bq + ch0);
        const float4 bu4 = *(const float4*)(bu + ch0);
#pragma unroll
        for (int nt = 0; nt < 2; ++nt) {
            const int n = nt * 16 + li;
            const size_t base = ((size_t)b * NN + n0 + n) * DD + ch0;
            ushort4 pk, pq, pu;
            pk.x = f2bfu(ak[nt][0] + bk4.x); pk.y = f2bfu(ak[nt][1] + bk4.y);
            pk.z = f2bfu(ak[nt][2] + bk4.z); pk.w = f2bfu(ak[nt][3] + bk4.w);
            pq.x = f2bfu(aq[nt][0] + bq4.x); pq.y = f2bfu(aq[nt][1] + bq4.y);
            pq.z = f2bfu(aq[nt][2] + bq4.z); pq.w = f2bfu(aq[nt][3] + bq4.w);
            pu.x = f2bfu(au[nt][0] + bu4.x); pu.y = f2bfu(au[nt][1] + bu4.y);
            pu.z = f2bfu(au[nt][2] + bu4.z); pu.w = f2bfu(au[nt][3] + bu4.w);
            *(ushort4*)((char*)kf + base * 2) = pk;
            *(ushort4*)((char*)qf + base * 2) = pq;
            *(ushort4*)((char*)uf + base * 2) = pu;
        }
    }
    __syncthreads();

    f32x4 a2[4][2];
#pragma unroll
    for (int mt = 0; mt < 4; ++mt) { a2[mt][0] = zero4; a2[mt][1] = zero4; }
    for (int ks = 0; ks < 8; ++ks) {
        f16x8 bh[2];
#pragma unroll
        for (int nt = 0; nt < 2; ++nt) {
            const int n = nt * 16 + li;
            bh[nt] = *(const f16x8*)(hv + n * 512 + ((ks * 64 + g * 16) ^ ((n & 7) << 4)));
        }
#pragma unroll
        for (int mt = 0; mt < 4; ++mt) {
            const f16x8 af = *(const f16x8*)(Wv2h + (size_t)(w * 64 + mt * 16 + li) * 256 + ks * 32 + g * 8);
            a2[mt][0] = mfma16(af, bh[0], a2[mt][0]);
            a2[mt][1] = mfma16(af, bh[1], a2[mt][1]);
        }
    }
    for (int ks = 0; ks < 16; ++ks) {
        f16x8 bx0 = *(const f16x8*)(xb + (size_t)li * 512 + ks * 32 + g * 8);
        f16x8 bx1 = *(const f16x8*)(xb + (size_t)(16 + li) * 512 + ks * 32 + g * 8);
#pragma unroll
        for (int mt = 0; mt < 4; ++mt) {
            const f16x8 af = *(const f16x8*)(Wvsh + (size_t)(w * 64 + mt * 16 + li) * 512 + ks * 32 + g * 8);
            a2[mt][0] = mfma16(af, bx0, a2[mt][0]);
            a2[mt][1] = mfma16(af, bx1, a2[mt][1]);
        }
    }
    __syncthreads();
#pragma unroll
    for (int mt = 0; mt < 4; ++mt) {
        const int ch0 = w * 64 + mt * 16 + g * 4;
        const float4 c4a = *(const float4*)(bv2 + ch0);
        const float4 c4b = *(const float4*)(bvs + ch0);
#pragma unroll
        for (int nt = 0; nt < 2; ++nt) {
            const int n = nt * 16 + li;
            f16x4 px;
            px.x = (f16)(a2[mt][nt][0] + c4a.x + c4b.x);
            px.y = (f16)(a2[mt][nt][1] + c4a.y + c4b.y);
            px.z = (f16)(a2[mt][nt][2] + c4a.z + c4b.z);
            px.w = (f16)(a2[mt][nt][3] + c4a.w + c4b.w);
            *(f16x4*)(hv + n * 512 + ((ch0 * 2) ^ ((n & 7) << 4))) = px;
        }
    }
    __syncthreads();

    f32x4 av[2] = {zero4, zero4};
    f32x4 ar[2][2];
    ar[0][0] = zero4; ar[0][1] = zero4; ar[1][0] = zero4; ar[1][1] = zero4;
    for (int ks = 0; ks < 8; ++ks) {
        f16x8 bh[2];
#pragma unroll
        for (int nt = 0; nt < 2; ++nt) {
            const int n = nt * 16 + li;
            bh[nt] = *(const f16x8*)(hv + n * 512 + ((ks * 64 + g * 16) ^ ((n & 7) << 4)));
        }
        const f16x8 afv = *(const f16x8*)(Wvvh + (size_t)(w * 16 + li) * 256 + ks * 32 + g * 8);
        av[0] = mfma16(afv, bh[0], av[0]);
        av[1] = mfma16(afv, bh[1], av[1]);
#pragma unroll
        for (int rt = 0; rt < 2; ++rt) {
            const f16x8 afr = *(const f16x8*)(Wresh + (size_t)((w * 2 + rt) * 16 + li) * 256 + ks * 32 + g * 8);
            ar[rt][0] = mfma16(afr, bh[0], ar[rt][0]);
            ar[rt][1] = mfma16(afr, bh[1], ar[rt][1]);
        }
    }
    {
        const int ch0 = w * 16 + g * 4;
        const float4 bb = *(const float4*)(bvv + ch0);
#pragma unroll
        for (int nt = 0; nt < 2; ++nt) {
            const int n = nt * 16 + li;
            ushort4 pk;
            pk.x = f2bfu(av[nt][0] + bb.x);
            pk.y = f2bfu(av[nt][1] + bb.y);
            pk.z = f2bfu(av[nt][2] + bb.z);
            pk.w = f2bfu(av[nt][3] + bb.w);
            *(ushort4*)((char*)vf_ws + (((size_t)b * NN + n0 + n) * DD + ch0) * 2) = pk;
        }
    }
#pragma unroll
    for (int rt = 0; rt < 2; ++rt) {
        const int ch0 = (w * 2 + rt) * 16 + g * 4;
        const float4 bb = *(const float4*)(bres + ch0);
#pragma unroll
        for (int nt = 0; nt < 2; ++nt) {
            const int n = nt * 16 + li;
            ushort4 pk;
            pk.x = f2bfu(ar[rt][nt][0] + bb.x);
            pk.y = f2bfu(ar[rt][nt][1] + bb.y);
            pk.z = f2bfu(ar[rt][nt][2] + bb.z);
            pk.w = f2bfu(ar[rt][nt][3] + bb.w);
            *(ushort4*)((char*)resid_ws + (((size_t)b * NN + n0 + n) * COUTN + ch0) * 2) = pk;
        }
    }
}

// ---------------------------------------------------------------------------
// Kernel 4 (fused): 8 n's per block, 8 waves (512 threads).
// Round 12: revert NPB 16->8 (round 11: 1 blk/CU exposed every barrier,
// +10 us); KEEP the 16B-vectorized phase-D gather from round 11 (swizzle is
// 16B-closed -> chunked stores cover identical bytes; math bit-identical).
// Structure otherwise = verified round 10.
// ---------------------------------------------------------------------------
__global__ __launch_bounds__(512, 4) void attn_fused(
    const float* __restrict__ posT, const u16* __restrict__ idx_ws,
    const bf16* __restrict__ kf_ws, const bf16* __restrict__ qf_ws,
    const bf16* __restrict__ uf_ws, const bf16* __restrict__ vf_ws,
    const bf16* __restrict__ resid_ws,
    const float* __restrict__ Wp1, const float* __restrict__ bp1,
    const float* __restrict__ gp1, const float* __restrict__ betap1,
    const f16* __restrict__ Wp2h, const float* __restrict__ bp2,
    const f16* __restrict__ Wa1h, const float* __restrict__ A1s,
    const float* __restrict__ A1b, const f16* __restrict__ Wth,
    const f16* __restrict__ Wendh, const float* __restrict__ bend,
    float* __restrict__ out) {
    __shared__ __align__(16) char pool[61440];
    f16*  ph16 = (f16*)(pool);
    f16*  S16  = (f16*)(pool);            // overlays ph16 (dead after C)
    f16*  L16T = (f16*)(pool);            // overlays S16 (dead after loop)
    f16*  peh  = (f16*)(pool + 20480);
    char* Hl   = pool + 20480;            // overlays peh (dead after D)
    f16*  V16  = (f16*)(pool + 40960);
    __shared__ __align__(16) f16 aggf[16 * 64];   // [nr][c] swizzled
    __shared__ int   nidx[NPB * KK];
    __shared__ float prel[NPB * KK][3];
    __shared__ float qcol[NPB][64], ucol[NPB][64];

    const int b  = blockIdx.x >> 8;           // NN/8 = 256 blocks per batch
    const int n0 = (blockIdx.x & 255) << 3;
    const int t = threadIdx.x;
    const int w = t >> 6, l = t & 63, g = l >> 4, li = l & 15;
    const int m4 = w & 3, nh = w >> 2;
    const size_t row0 = (size_t)b * NN + n0;
    const f32x4 zero4 = {0.f, 0.f, 0.f, 0.f};

    if (t < NPB * KK) nidx[t] = (int)idx_ws[row0 * KK + t];
    __syncthreads();

    // A: per-n q/u columns + prel
    {
        const int n = t >> 6, c = t & 63;
        qcol[n][c] = bf2f(qf_ws[(row0 + n) * DD + c]);
        ucol[n][c] = bf2f(uf_ws[(row0 + n) * DD + c]);
    }
    if (t < 480) {
        const int r = t / 3, d = t - r * 3;
        const int n = r / KK;
        prel[r][d] = posT[(row0 + n) * 3 + d] - posT[((size_t)b * NN + nidx[r]) * 3 + d];
    }
    __syncthreads();

    // B: pos_mlp l1 (3->64, BN, ReLU) -> ph16 packed+swizzled
    for (int u = t; u < 160 * 32; u += 512) {
        const int r = u >> 5, c0 = (u & 31) << 1;
        float a0 = Wp1[c0 * 3 + 0] * prel[r][0] + Wp1[c0 * 3 + 1] * prel[r][1]
                 + Wp1[c0 * 3 + 2] * prel[r][2] + bp1[c0];
        float a1 = Wp1[c0 * 3 + 3] * prel[r][0] + Wp1[c0 * 3 + 4] * prel[r][1]
                 + Wp1[c0 * 3 + 5] * prel[r][2] + bp1[c0 + 1];
        a0 = gp1[c0] * a0 * BN_INV + betap1[c0];
        a1 = gp1[c0 + 1] * a1 * BN_INV + betap1[c0 + 1];
        h2 pr; pr.x = (f16)fmaxf(a0, 0.f); pr.y = (f16)fmaxf(a1, 0.f);
        *(unsigned*)((char*)ph16 + (r * 128 + ((c0 * 2) ^ ((r & 7) << 4)))) =
            __builtin_bit_cast(unsigned, pr);
    }
    __syncthreads();

    // C: pos_mlp l2 via MFMA (M=64 co, N=160 nk, K=64) -> peh[nk][co]+bp2
    {
        f32x4 d[5];
#pragma unroll
        for (int j = 0; j < 5; ++j) d[j] = zero4;
#pragma unroll
        for (int ks = 0; ks < 2; ++ks) {
            const f16x8 af = *(const f16x8*)(Wp2h + (m4 * 16 + li) * 64 + ks * 32 + g * 8);
#pragma unroll
            for (int j = 0; j < 5; ++j) {
                const int r = (nh * 5 + j) * 16 + li;
                const f16x8 bf = *(const f16x8*)((const char*)ph16 +
                                  (r * 128 + ((ks * 64 + g * 16) ^ ((r & 7) << 4))));
                d[j] = mfma16(af, bf, d[j]);
            }
        }
        const int ch0 = m4 * 16 + g * 4;
        const float4 b4 = *(const float4*)(bp2 + ch0);
#pragma unroll
        for (int j = 0; j < 5; ++j) {
            const int r = (nh * 5 + j) * 16 + li;
            f16x4 pk;
            pk.x = (f16)(d[j][0] + b4.x);
            pk.y = (f16)(d[j][1] + b4.y);
            pk.z = (f16)(d[j][2] + b4.z);
            pk.w = (f16)(d[j][3] + b4.w);
            *(f16x4*)((char*)peh + (r * 128 + ((ch0 * 2) ^ ((r & 7) << 4)))) = pk;
        }
    }
    __syncthreads();

    // D: gather + combine, 16B-vectorized (8 channels/chunk) -> S16, V16
    for (int u = t; u < 160 * 8; u += 512) {
        const int r = u >> 3, cg = (u & 7) << 3;
        const int n = r / KK;
        const size_t nb = (((size_t)b * NN + nidx[r]) * DD + cg) * 2;
        const uint4 kq = *(const uint4*)((const char*)kf_ws + nb);
        const uint4 uq = *(const uint4*)((const char*)uf_ws + nb);
        const uint4 vq = *(const uint4*)((const char*)vf_ws + nb);
        const int sw = (cg * 2) ^ ((r & 7) << 4);
        const uint4 pw = *(const uint4*)((const char*)peh + (r * 128 + sw));
        uint4 sres, vres;
#define PROC(comp, off) { \
        const float k0 = lo2f(kq.comp), k1 = hi2f(kq.comp); \
        const float u0 = lo2f(uq.comp), u1 = hi2f(uq.comp); \
        const float v0 = lo2f(vq.comp), v1 = hi2f(vq.comp); \
        const h2 pp = __builtin_bit_cast(h2, pw.comp); \
        const float add0 = ucol[n][cg + off]     + (float)pp.x; \
        const float add1 = ucol[n][cg + off + 1] + (float)pp.y; \
        h2 s; s.x = (f16)(-(k0 + u0) + qcol[n][cg + off] + add0); \
              s.y = (f16)(-(k1 + u1) + qcol[n][cg + off + 1] + add1); \
        h2 v; v.x = (f16)(v0 - u0 + add0); v.y = (f16)(v1 - u1 + add1); \
        sres.comp = __builtin_bit_cast(unsigned, s); \
        vres.comp = __builtin_bit_cast(unsigned, v); }
        PROC(x, 0) PROC(y, 2) PROC(z, 4) PROC(w, 6)
#undef PROC
        *(uint4*)((char*)S16 + (r * 128 + sw)) = sres;
        *(uint4*)((char*)V16 + (r * 128 + sw)) = vres;
    }
    __syncthreads();

    // GEMM loop: 4 chunks of 64 H-rows. GEMM1: wave = (m4 M-tile, nh nt-half);
    // GEMM2: wave w owns cr-tile w, K = chunk's 64 rows.
    f32x4 acc2[10];
#pragma unroll
    for (int j = 0; j < 10; ++j) acc2[j] = zero4;

    for (int c4 = 0; c4 < 4; ++c4) {
        const int hrb = c4 * 64 + m4 * 16;
        f32x4 d1[5];
#pragma unroll
        for (int j = 0; j < 5; ++j) d1[j] = zero4;
#pragma unroll
        for (int ks = 0; ks < 2; ++ks) {
            const f16x8 af = *(const f16x8*)(Wa1h + (hrb + li) * 64 + ks * 32 + g * 8);
#pragma unroll
            for (int j = 0; j < 5; ++j) {
                const int r = (nh * 5 + j) * 16 + li;
                const f16x8 sfv = *(const f16x8*)((const char*)S16 +
                                   (r * 128 + ((ks * 64 + g * 16) ^ ((r & 7) << 4))));
                d1[j] = mfma16(af, sfv, d1[j]);
            }
        }
        const float4 as4 = *(const float4*)(A1s + hrb + g * 4);
        const float4 ab4 = *(const float4*)(A1b + hrb + g * 4);
        __syncthreads();   // prior chunk's GEMM2 (and c4=0: phase D) done
#pragma unroll
        for (int j = 0; j < 5; ++j) {
            const int col = (nh * 5 + j) * 16 + li;
            const int ch0 = m4 * 16 + g * 4;   // chunk-local H row
            f16x4 pk;
            pk.x = (f16)fmaxf(as4.x * d1[j][0] + ab4.x, 0.f);
            pk.y = (f16)fmaxf(as4.y * d1[j][1] + ab4.y, 0.f);
            pk.z = (f16)fmaxf(as4.z * d1[j][2] + ab4.z, 0.f);
            pk.w = (f16)fmaxf(as4.w * d1[j][3] + ab4.w, 0.f);
            *(f16x4*)(Hl + col * 128 + ((ch0 * 2) ^ ((col & 7) << 4))) = pk;
        }
        __syncthreads();
#pragma unroll
        for (int ks2 = 0; ks2 < 2; ++ks2) {
            const f16x8 bf = *(const f16x8*)(Wth + (size_t)(w * 16 + li) * AHH + c4 * 64 + ks2 * 32 + g * 8);
#pragma unroll
            for (int nt = 0; nt < 10; ++nt) {
                const int col = nt * 16 + li;
                const f16x8 ha = *(const f16x8*)(Hl + col * 128 + ((ks2 * 64 + g * 16) ^ ((col & 7) << 4)));
                acc2[nt] = mfma16(ha, bf, acc2[nt]);
            }
        }
    }
    __syncthreads();   // Hl/S16 reads done before L16T overlays

    // logits L16T[row=nk][col=cr], XOR((row&3)<<5)
#pragma unroll
    for (int nt = 0; nt < 10; ++nt) {
        const f32x4 d = acc2[nt];
#pragma unroll
        for (int j = 0; j < 4; ++j) {
            const int row = nt * 16 + g * 4 + j;
            *(f16*)((char*)L16T + (row * 256 + (((w * 16 + li) * 2) ^ ((row & 3) << 5)))) =
                (f16)d[j];
        }
    }
    __syncthreads();

    // softmax over k + aggregate with V16 -> aggf[nr][c] f16 swizzled
    {
        const int cr = t & 127, c = cr >> 1, rr = cr & 1;
        const int nbase = (t >> 7) * 2;
        for (int p = 0; p < 2; ++p) {
            const int n = nbase + p;
            float lv[20];
#pragma unroll
            for (int k = 0; k < 20; ++k) {
                const int row = n * KK + k;
                lv[k] = (float)*(const f16*)((const char*)L16T +
                          (row * 256 + ((cr * 2) ^ ((row & 3) << 5))));
            }
            float m = lv[0];
#pragma unroll
            for (int k = 1; k < 20; ++k) m = fmaxf(m, lv[k]);
            float s = 0.f, a = 0.f;
#pragma unroll
            for (int k = 0; k < 20; ++k) {
                const float e = __expf(lv[k] - m);
                s += e;
                const int r = n * KK + k;
                const float vv = (float)*(const f16*)((const char*)V16 +
                                   (r * 128 + ((c * 2) ^ ((r & 7) << 4))));
                a += e * vv;
            }
            const int arow = n * 2 + rr;
            *(f16*)((char*)aggf + (arow * 128 + ((c * 2) ^ ((arow & 7) << 4)))) = (f16)(a / s);
        }
    }
    __syncthreads();

    // conv_end via MFMA: M=128 o (wave w -> o-tile w), N=16 nr, K=64.
    // D col li -> output offset 2n0+li (64B-coalesced stores).
    {
        f32x4 dc = zero4;
#pragma unroll
        for (int ks = 0; ks < 2; ++ks) {
            const f16x8 af = *(const f16x8*)(Wendh + (size_t)(w * 16 + li) * 64 + ks * 32 + g * 8);
            const f16x8 bfr = *(const f16x8*)((const char*)aggf +
                               (li * 128 + (((ks * 32 + g * 8) * 2) ^ ((li & 7) << 4))));
            dc = mfma16(af, bfr, dc);
        }
        const int nloc = li >> 1;
#pragma unroll
        for (int j = 0; j < 4; ++j) {
            const int o = w * 16 + g * 4 + j;
            const float rv = bf2f(resid_ws[(row0 + nloc) * COUTN + o]);
            out[(size_t)b * COUTN * (NN * UPF) + (size_t)o * (NN * UPF) + 2 * n0 + li] =
                dc[j] + bend[o] + rv;
        }
    }
}

extern "C" void kernel_launch(void* const* d_in, const int* in_sizes, int n_in,
                              void* d_out, int out_size, void* d_ws, size_t ws_size,
                              hipStream_t stream) {
    const float* pos        = (const float*)d_in[0];
    const float* key_feat   = (const float*)d_in[1];
    const float* query_feat = (const float*)d_in[2];
    const float* upfeat     = (const float*)d_in[3];
    const float* Wv1 = (const float*)d_in[4];
    const float* bv1 = (const float*)d_in[5];
    const float* Wv2 = (const float*)d_in[6];
    const float* bv2 = (const float*)d_in[7];
    const float* Wvs = (const float*)d_in[8];
    const float* bvs = (const float*)d_in[9];
    const float* Wk  = (const float*)d_in[10];
    const float* bk  = (const float*)d_in[11];
    const float* Wq  = (const float*)d_in[12];
    const float* bq  = (const float*)d_in[13];
    const float* Wvv = (const float*)d_in[14];
    const float* bvv = (const float*)d_in[15];
    const float* Wu  = (const float*)d_in[16];
    const float* bu  = (const float*)d_in[17];
    const float* Wp1 = (const float*)d_in[18];
    const float* bp1 = (const float*)d_in[19];
    const float* gp1 = (const float*)d_in[20];
    const float* betap1 = (const float*)d_in[21];
    const float* Wp2 = (const float*)d_in[22];
    const float* bp2 = (const float*)d_in[23];
    const float* Wa1 = (const float*)d_in[24];
    const float* ba1 = (const float*)d_in[25];
    const float* ga1 = (const float*)d_in[26];
    const float* betaa1 = (const float*)d_in[27];
    const float* Wt   = (const float*)d_in[28];
    const float* bt   = (const float*)d_in[29];
    const float* Wend = (const float*)d_in[30];
    const float* bend = (const float*)d_in[31];
    const float* Wres = (const float*)d_in[32];
    const float* bres = (const float*)d_in[33];
    float* out = (float*)d_out;
    (void)out_size; (void)bt;   // bt cancels in softmax (uniform over k)

    const bool sizes_ok = (n_in >= 34)
        && (in_sizes[0] == BB * 3 * NN)
        && (in_sizes[1] == BB * CIN * NN)
        && (in_sizes[4] == CIN * 2 * CIN)
        && (in_sizes[28] == AHH * DD * UPF)
        && (in_sizes[32] == COUTN * CIN);

    size_t off = 0;
    auto take = [&](size_t bytes) { size_t o = off; off = (off + bytes + 255) & ~(size_t)255; return o; };
    const size_t off_posT  = take((size_t)BB * NN * 3 * sizeof(float));
    const size_t off_idx   = take((size_t)BB * NN * KK * sizeof(u16));
    const size_t off_vf    = take((size_t)BB * NN * DD * sizeof(bf16));
    const size_t off_kf    = take((size_t)BB * NN * DD * sizeof(bf16));
    const size_t off_qf    = take((size_t)BB * NN * DD * sizeof(bf16));
    const size_t off_uf    = take((size_t)BB * NN * DD * sizeof(bf16));
    const size_t off_resid = take((size_t)BB * NN * COUTN * sizeof(bf16));
    const size_t off_wa1h  = take((size_t)AHH * DD * sizeof(f16));
    const size_t off_wp2h  = take((size_t)PHH * DD * sizeof(f16));
    const size_t off_wth   = take((size_t)COUTN * AHH * sizeof(f16));
    const size_t off_a1s   = take((size_t)AHH * sizeof(float));
    const size_t off_a1b   = take((size_t)AHH * sizeof(float));
    const size_t off_wendh = take((size_t)COUTN * DD * sizeof(f16));
    const size_t off_wv1h  = take((size_t)CIN * 2 * CIN * sizeof(f16));
    const size_t off_wv2h  = take((size_t)CIN * CIN * sizeof(f16));
    const size_t off_wvsh  = take((size_t)CIN * 2 * CIN * sizeof(f16));
    const size_t off_wvvh  = take((size_t)DD * CIN * sizeof(f16));
    const size_t off_wresh = take((size_t)COUTN * CIN * sizeof(f16));
    const size_t off_wkh   = take((size_t)DD * CIN * sizeof(f16));
    const size_t off_wqh   = take((size_t)DD * CIN * sizeof(f16));
    const size_t off_wuh   = take((size_t)DD * CIN * sizeof(f16));
    const size_t off_xkq   = take((size_t)BB * NN * 512 * sizeof(f16));
    const size_t off_xu    = take((size_t)BB * NN * 256 * sizeof(f16));
    const size_t NEED = off;

    if (!sizes_ok) return;
    if (ws_size < NEED) {
        sentinel_kernel<<<1, 64, 0, stream>>>(out);
        return;
    }

    char* ws = (char*)d_ws;
    float* posT_ws  = (float*)(ws + off_posT);
    u16*   idx_ws   = (u16*)(ws + off_idx);
    bf16*  vf_ws    = (bf16*)(ws + off_vf);
    bf16*  kf_ws    = (bf16*)(ws + off_kf);
    bf16*  qf_ws    = (bf16*)(ws + off_qf);
    bf16*  uf_ws    = (bf16*)(ws + off_uf);
    bf16*  resid_ws = (bf16*)(ws + off_resid);
    f16*   Wa1h_ws  = (f16*)(ws + off_wa1h);
    f16*   Wp2h_ws  = (f16*)(ws + off_wp2h);
    f16*   Wth_ws   = (f16*)(ws + off_wth);
    float* A1s_ws   = (float*)(ws + off_a1s);
    float* A1b_ws   = (float*)(ws + off_a1b);
    f16*   Wendh_ws = (f16*)(ws + off_wendh);
    f16*   Wv1h_ws  = (f16*)(ws + off_wv1h);
    f16*   Wv2h_ws  = (f16*)(ws + off_wv2h);
    f16*   Wvsh_ws  = (f16*)(ws + off_wvsh);
    f16*   Wvvh_ws  = (f16*)(ws + off_wvvh);
    f16*   Wresh_ws = (f16*)(ws + off_wresh);
    f16*   Wkh_ws   = (f16*)(ws + off_wkh);
    f16*   Wqh_ws   = (f16*)(ws + off_wqh);
    f16*   Wuh_ws   = (f16*)(ws + off_wuh);
    f16*   xkqT_ws  = (f16*)(ws + off_xkq);
    f16*   xuT_ws   = (f16*)(ws + off_xu);

    prep_kernel<<<(CIN * 2 * CIN + 255) / 256, 256, 0, stream>>>(
        Wa1, Wp2, Wend, Wt, Wv1, Wv2, Wvs, Wvv, Wres, Wk, Wq, Wu,
        ba1, ga1, betaa1,
        Wa1h_ws, Wp2h_ws, Wth_ws, A1s_ws, A1b_ws, Wendh_ws,
        Wv1h_ws, Wv2h_ws, Wvsh_ws, Wvvh_ws, Wresh_ws, Wkh_ws, Wqh_ws, Wuh_ws);
    xpose_kernel<<<dim3(BB * (NN / 64), 12), 256, 0, stream>>>(
        key_feat, query_feat, upfeat, xkqT_ws, xuT_ws);
    knn_kernel<<<BB * NN, 256, 0, stream>>>(pos, idx_ws, posT_ws);
    value_mfma<<<BB * (NN / 32), 256, 0, stream>>>(xkqT_ws, xuT_ws,
        Wv1h_ws, bv1, Wv2h_ws, bv2, Wvsh_ws, bvs, Wvvh_ws, bvv, Wresh_ws, bres,
        Wkh_ws, bk, Wqh_ws, bq, Wuh_ws, bu,
        vf_ws, resid_ws, kf_ws, qf_ws, uf_ws);
    attn_fused<<<BB * (NN / NPB), 512, 0, stream>>>(posT_ws, idx_ws,
        kf_ws, qf_ws, uf_ws, vf_ws, resid_ws,
        Wp1, bp1, gp1, betap1, Wp2h_ws, bp2,
        Wa1h_ws, A1s_ws, A1b_ws, Wth_ws, Wendh_ws, bend, out);
}

// Round 13
// 409.405 us; speedup vs baseline: 1.0645x; 1.0245x over previous
//
#include <hip/hip_runtime.h>
#include <hip/hip_bf16.h>
#include <math.h>

#define BB 8
#define NN 2048
#define KK 20
#define UPF 2
#define CIN 256
#define DD 64
#define COUTN 128
#define PHH 64
#define AHH 256
#define BN_INV 0.9999950000374997f   // np.float32(1/sqrt(1+1e-5))
#define NPB 8                        // attn n's per block (8 waves; 16 regressed: 1 blk/CU)

typedef __hip_bfloat16 bf16;
typedef unsigned short u16;
typedef unsigned long long u64;
typedef _Float16 f16;
typedef _Float16 h2   __attribute__((ext_vector_type(2)));
typedef _Float16 f16x4 __attribute__((ext_vector_type(4)));
typedef _Float16 f16x8 __attribute__((ext_vector_type(8)));
typedef float    f32x4 __attribute__((ext_vector_type(4)));

static __device__ __forceinline__ float bf2f(const bf16 v) { return __bfloat162float(v); }
static __device__ __forceinline__ bf16  f2bf(const float v) { return __float2bfloat16(v); }
static __device__ __forceinline__ u16   f2bfu(const float v) {
    return __builtin_bit_cast(u16, __float2bfloat16(v));
}
// exact bf16(bits)->f32
static __device__ __forceinline__ float lo2f(const unsigned v) { return __builtin_bit_cast(float, v << 16); }
static __device__ __forceinline__ float hi2f(const unsigned v) { return __builtin_bit_cast(float, v & 0xFFFF0000u); }

static __device__ __forceinline__ f32x4 mfma16(const f16x8 a, const f16x8 b, const f32x4 c) {
    return __builtin_amdgcn_mfma_f32_16x16x32_f16(a, b, c, 0, 0, 0);
}
// order-preserving float->u32 map: ascending float => ascending unsigned.
static __device__ __forceinline__ unsigned fmap(const float f) {
    unsigned u = __builtin_bit_cast(unsigned, f);
    return (u >> 31) ? ~u : (u | 0x80000000u);
}

__global__ void sentinel_kernel(float* out) {
    if (threadIdx.x == 0 && blockIdx.x == 0) out[0] = 100.0f;
}

// ---------------------------------------------------------------------------
// Kernel 0: weight prep (f16 k-contiguous rows for MFMA; Wth transposed;
// A1s/A1b folded BN; Wendh f16 for the conv_end MFMA).
// ---------------------------------------------------------------------------
__global__ __launch_bounds__(256) void prep_kernel(
    const float* __restrict__ Wa1, const float* __restrict__ Wp2,
    const float* __restrict__ Wend, const float* __restrict__ Wt,
    const float* __restrict__ Wv1, const float* __restrict__ Wv2,
    const float* __restrict__ Wvs, const float* __restrict__ Wvv,
    const float* __restrict__ Wres,
    const float* __restrict__ Wk, const float* __restrict__ Wq,
    const float* __restrict__ Wu,
    const float* __restrict__ ba1, const float* __restrict__ ga1,
    const float* __restrict__ betaa1,
    f16* __restrict__ Wa1h, f16* __restrict__ Wp2h, f16* __restrict__ Wth,
    float* __restrict__ A1s, float* __restrict__ A1b,
    f16* __restrict__ Wendh,
    f16* __restrict__ Wv1h, f16* __restrict__ Wv2h, f16* __restrict__ Wvsh,
    f16* __restrict__ Wvvh, f16* __restrict__ Wresh,
    f16* __restrict__ Wkh, f16* __restrict__ Wqh, f16* __restrict__ Wuh) {
    const int t = blockIdx.x * 256 + threadIdx.x;
    if (t < AHH * DD)        Wa1h[t] = (f16)Wa1[t];
    if (t < PHH * DD)        Wp2h[t] = (f16)Wp2[t];
    if (t < COUTN * AHH)     { int cr = t >> 8, hh = t & 255; Wth[t] = (f16)Wt[hh * COUTN + cr]; }
    if (t < AHH) {
        float gsc = ga1[t] * BN_INV;
        A1s[t] = gsc;
        A1b[t] = gsc * ba1[t] + betaa1[t];
    }
    if (t < COUTN * DD)      Wendh[t] = (f16)Wend[t];
    if (t < CIN * 2 * CIN)   Wv1h[t] = (f16)Wv1[t];
    if (t < CIN * CIN)       Wv2h[t] = (f16)Wv2[t];
    if (t < CIN * 2 * CIN)   Wvsh[t] = (f16)Wvs[t];
    if (t < DD * CIN)        Wvvh[t] = (f16)Wvv[t];
    if (t < COUTN * CIN)     Wresh[t] = (f16)Wres[t];
    if (t < DD * CIN)        Wkh[t]  = (f16)Wk[t];
    if (t < DD * CIN)        Wqh[t]  = (f16)Wq[t];
    if (t < DD * CIN)        Wuh[t]  = (f16)Wu[t];
}

// ---------------------------------------------------------------------------
// Kernel 0b: transpose key/query/upfeat (B,C,N) fp32 -> point-major f16.
// ---------------------------------------------------------------------------
__global__ __launch_bounds__(256) void xpose_kernel(
    const float* __restrict__ key_feat, const float* __restrict__ query_feat,
    const float* __restrict__ upfeat,
    f16* __restrict__ xkqT, f16* __restrict__ xuT) {
    __shared__ float tile[64][65];
    const int b  = blockIdx.x >> 5;
    const int n0 = (blockIdx.x & 31) << 6;
    const int y  = blockIdx.y;
    const int src = y >> 2;
    const int ct  = (y & 3) << 6;
    const int t = threadIdx.x;
    const float* xin = (src == 0) ? key_feat : (src == 1) ? query_feat : upfeat;
    f16* dst; int CT, cb;
    if (src < 2) { dst = xkqT; CT = 512; cb = src * 256 + ct; }
    else         { dst = xuT;  CT = 256; cb = ct; }
    for (int u = t; u < 64 * 64; u += 256) {
        const int c = u >> 6, j = u & 63;
        tile[c][j] = xin[((size_t)b * CIN + ct + c) * NN + n0 + j];
    }
    __syncthreads();
    for (int u = t; u < 64 * 32; u += 256) {
        const int n = u >> 5, c0 = (u & 31) << 1;
        h2 pr; pr.x = (f16)tile[c0][n]; pr.y = (f16)tile[c0 + 1][n];
        ((unsigned*)dst)[(((size_t)b * NN + n0 + n) * CT + cb + c0) >> 1] =
            __builtin_bit_cast(unsigned, pr);
    }
}

// ---------------------------------------------------------------------------
// Kernel 1: KNN — block per query, adaptive single-histogram select,
// REGISTER-RESIDENT keys (round 13): each thread owns 8 points
// (m = t + j*256) and keeps their fmap keys in 8 VGPRs. Deletes the
// dist[2048] LDS array and all its re-scan traffic; LDS drops to ~3 KB.
// Selection semantics identical to the verified round-9/round-5 versions.
// ---------------------------------------------------------------------------
__global__ __launch_bounds__(256) void knn_kernel(const float* __restrict__ pos,
                                                  u16* __restrict__ idx_out,
                                                  float* __restrict__ posT) {
    __shared__ int   hist[512];
    __shared__ unsigned rmin[4], rmax[4];
    __shared__ u64   cbuf[64];
    __shared__ float q[3];
    __shared__ unsigned minkS;
    __shared__ int   shiftS, jstarS, cntS, bcastS;
    __shared__ u64   ltbuf[KK];
    __shared__ int   tiebuf[64];
    __shared__ int   ri4[4];
    __shared__ unsigned prefS;
    __shared__ int   knS, cnt_lt, cnt_eq;

    const int b = blockIdx.x / NN;
    const int n = blockIdx.x % NN;
    const int t = threadIdx.x;
    const float* pb = pos + (size_t)b * 3 * NN;
    const size_t rowKK = ((size_t)b * NN + n) * KK;

    if (t < 3) {
        float v = pb[(size_t)t * NN + n];
        q[t] = v;
        posT[((size_t)b * NN + n) * 3 + t] = v;
    }
    if (t == 0) { prefS = 0u; knS = KK; cnt_lt = 0; cnt_eq = 0; cntS = 0; jstarS = 0; }
    __syncthreads();
    const float qx = q[0], qy = q[1], qz = q[2];
    const float sqq = __fadd_rn(__fadd_rn(__fmul_rn(qx, qx), __fmul_rn(qy, qy)), __fmul_rn(qz, qz));
    unsigned key[8];
    unsigned kmin = 0xFFFFFFFFu, kmax = 0u;
#pragma unroll
    for (int j = 0; j < 8; ++j) {
        const int m = t + j * 256;
        float px = pb[m];
        float py = pb[NN + m];
        float pz = pb[2 * NN + m];
        float sqm = __fadd_rn(__fadd_rn(__fmul_rn(px, px), __fmul_rn(py, py)), __fmul_rn(pz, pz));
        float dt  = __fadd_rn(__fadd_rn(__fmul_rn(qx, px), __fmul_rn(qy, py)), __fmul_rn(qz, pz));
        const float d = __fsub_rn(__fadd_rn(sqq, sqm), __fmul_rn(2.0f, dt));
        key[j] = fmap(d);
        kmin = min(kmin, key[j]);
        kmax = max(kmax, key[j]);
    }
#pragma unroll
    for (int off = 32; off > 0; off >>= 1) {
        kmin = min(kmin, (unsigned)__shfl_down((int)kmin, off, 64));
        kmax = max(kmax, (unsigned)__shfl_down((int)kmax, off, 64));
    }
    if ((t & 63) == 0) { rmin[t >> 6] = kmin; rmax[t >> 6] = kmax; }
    hist[t] = 0; hist[256 + t] = 0;
    __syncthreads();
    if (t == 0) {
        const unsigned mn = min(min(rmin[0], rmin[1]), min(rmin[2], rmin[3]));
        const unsigned mx = max(max(rmax[0], rmax[1]), max(rmax[2], rmax[3]));
        const unsigned range = mx - mn;
        minkS  = mn;
        shiftS = (range >= 256u) ? (24 - __clz((int)range)) : 0;
    }
    __syncthreads();
    const unsigned mink = minkS;
    const int sh = shiftS;

    // histogram over adaptive bins (from registers; 2-way sub-hist)
#pragma unroll
    for (int j = 0; j < 8; ++j) {
        const unsigned bin = (key[j] - mink) >> sh;
        atomicAdd(&hist[((unsigned)(t & 1) << 8) | bin], 1);
    }
    __syncthreads();
    if (t < 64) {
        const int h0  = hist[4 * t + 0] + hist[256 + 4 * t + 0];
        const int h1  = hist[4 * t + 1] + hist[256 + 4 * t + 1];
        const int h2v = hist[4 * t + 2] + hist[256 + 4 * t + 2];
        const int h3  = hist[4 * t + 3] + hist[256 + 4 * t + 3];
        const int lsum = h0 + h1 + h2v + h3;
        int incl = lsum;
#pragma unroll
        for (int off = 1; off < 64; off <<= 1) {
            int v = __shfl_up(incl, off, 64);
            if (t >= off) incl += v;
        }
        const int excl = incl - lsum;
        if (excl < KK && excl + lsum >= KK) {
            int bsel;
            if      (excl + h0 >= KK)            bsel = 0;
            else if (excl + h0 + h1 >= KK)       bsel = 1;
            else if (excl + h0 + h1 + h2v >= KK) bsel = 2;
            else                                 bsel = 3;
            jstarS = 4 * t + bsel;
        }
    }
    __syncthreads();
    const unsigned jstar = (unsigned)jstarS;

    // collect all candidates with bin <= j* (from registers)
#pragma unroll
    for (int j = 0; j < 8; ++j) {
        if (((key[j] - mink) >> sh) <= jstar) {
            const int p = atomicAdd(&cntS, 1);
            if (p < 64) cbuf[p] = ((u64)key[j] << 32) | (unsigned)(t + j * 256);
        }
    }
    __syncthreads();
    const int total = cntS;

    if (total <= 64) {
        // exact: rank-sort <=64 (key,idx) u64s; first KK ranks are the answer
        if (t < 64) {
            u64 v = (t < total) ? cbuf[t] : 0xFFFFFFFFFFFFFFFFull;
            int rank = 0;
#pragma unroll 16
            for (int j = 0; j < 64; ++j) {
                const u64 o = (u64)__shfl((long long)v, j, 64);
                if (o < v) ++rank;
            }
            if (t < total && rank < KK) idx_out[rowKK + rank] = (u16)(v & 0xFFFFu);
        }
        return;
    }

    // ---- fallback: verified 4-pass radix select (register keys) ----
    for (int pass = 0; pass < 4; ++pass) {
        const int shift = 24 - 8 * pass;
        const unsigned pm = (pass == 0) ? 0u : (0xFFFFFFFFu << (32 - 8 * pass));
        hist[t] = 0;
        __syncthreads();
        const unsigned pref = prefS;
        const int kn = knS;
#pragma unroll
        for (int j = 0; j < 8; ++j) {
            if ((key[j] & pm) == pref)
                atomicAdd(&hist[(key[j] >> shift) & 255], 1);
        }
        __syncthreads();
        if (t < 64) {
            const int h0 = hist[4 * t + 0], h1 = hist[4 * t + 1];
            const int h2v = hist[4 * t + 2], h3 = hist[4 * t + 3];
            const int lsum = h0 + h1 + h2v + h3;
            int incl = lsum;
#pragma unroll
            for (int off = 1; off < 64; off <<= 1) {
                int v = __shfl_up(incl, off, 64);
                if (t >= off) incl += v;
            }
            const int excl = incl - lsum;
            if (excl < kn && excl + lsum >= kn) {
                int bsel, cb;
                if      (excl + h0 >= kn)            { bsel = 0; cb = excl; }
                else if (excl + h0 + h1 >= kn)       { bsel = 1; cb = excl + h0; }
                else if (excl + h0 + h1 + h2v >= kn) { bsel = 2; cb = excl + h0 + h1; }
                else                                 { bsel = 3; cb = excl + h0 + h1 + h2v; }
                knS = kn - cb;
                prefS = pref | ((unsigned)(4 * t + bsel) << shift);
            }
        }
        __syncthreads();
    }

    const unsigned T = prefS;
#pragma unroll
    for (int j = 0; j < 8; ++j) {
        const unsigned k = key[j];
        const int m = t + j * 256;
        if (k < T) {
            int p = atomicAdd(&cnt_lt, 1);
            ltbuf[p] = ((u64)k << 32) | (unsigned)m;
        } else if (k == T) {
            int p = atomicAdd(&cnt_eq, 1);
            if (p < 64) tiebuf[p] = m;
        }
    }
    __syncthreads();
    const int nlt = cnt_lt, neq_need = knS, ceq = cnt_eq;

    if (t < 64) {
        u64 v = (t < nlt) ? ltbuf[t] : 0xFFFFFFFFFFFFFFFFull;
        int rank = 0;
#pragma unroll
        for (int j = 0; j < KK; ++j) {
            const u64 o = (u64)__shfl((long long)v, j, 64);
            if (o < v) ++rank;
        }
        if (t < nlt) idx_out[rowKK + rank] = (u16)(v & 0xFFFFu);
    }
    if (ceq <= 64) {
        if (t < 64) {
            int ti = (t < ceq) ? tiebuf[t] : 0x7FFFFFFF;
            int rk = 0;
            for (int j = 0; j < 64; ++j) {
                const int o = __shfl(ti, j, 64);
                if (o < ti) ++rk;
            }
            if (t < ceq && rk < neq_need) idx_out[rowKK + nlt + rk] = (u16)ti;
        }
    } else {
        // degenerate mass-tie fallback: iterative min-index among key==T;
        // the owner thread (m&255==t, j=m>>8) poisons its register copy.
        for (int iter = 0; iter < neq_need; ++iter) {
            int bi = NN;
#pragma unroll
            for (int j = 0; j < 8; ++j)
                if (key[j] == T) { const int m = t + j * 256; if (m < bi) bi = m; }
            for (int off = 32; off > 0; off >>= 1) {
                int i2 = __shfl_down(bi, off, 64);
                bi = min(bi, i2);
            }
            if ((t & 63) == 0) ri4[t >> 6] = bi;
            __syncthreads();
            if (t == 0) {
                int i0 = min(min(ri4[0], ri4[1]), min(ri4[2], ri4[3]));
                idx_out[rowKK + nlt + iter] = (u16)i0;
                bcastS = i0;
            }
            __syncthreads();
            const int i0 = bcastS;
            if ((i0 & 255) == t) {
                const int j0 = i0 >> 8;
#pragma unroll
                for (int j = 0; j < 8; ++j) if (j == j0) key[j] = 0xFFFFFFFFu;
            }
        }
    }
}

// ---------------------------------------------------------------------------
// Kernel 2 (MFMA): value path + fused kf/qf/uf projections (verified r10).
// ---------------------------------------------------------------------------
__global__ __launch_bounds__(256) void value_mfma(
    const f16* __restrict__ xkqT, const f16* __restrict__ xuT,
    const f16* __restrict__ Wv1h, const float* __restrict__ bv1,
    const f16* __restrict__ Wv2h, const float* __restrict__ bv2,
    const f16* __restrict__ Wvsh, const float* __restrict__ bvs,
    const f16* __restrict__ Wvvh, const float* __restrict__ bvv,
    const f16* __restrict__ Wresh, const float* __restrict__ bres,
    const f16* __restrict__ Wkh, const float* __restrict__ bk,
    const f16* __restrict__ Wqh, const float* __restrict__ bq,
    const f16* __restrict__ Wuh, const float* __restrict__ bu,
    bf16* __restrict__ vf_ws, bf16* __restrict__ resid_ws,
    bf16* __restrict__ kf, bf16* __restrict__ qf, bf16* __restrict__ uf) {
    __shared__ __align__(16) char hv[32 * 512];
    const int b  = blockIdx.x >> 6;
    const int n0 = (blockIdx.x & 63) << 5;
    const int t = threadIdx.x;
    const int w = t >> 6, l = t & 63, g = l >> 4, li = l & 15;
    const f16* xb = xkqT + ((size_t)b * NN + n0) * 512;
    const f32x4 zero4 = {0.f, 0.f, 0.f, 0.f};

    f32x4 a1[4][2];
    f32x4 ak[2] = {zero4, zero4}, aq[2] = {zero4, zero4};
#pragma unroll
    for (int mt = 0; mt < 4; ++mt) { a1[mt][0] = zero4; a1[mt][1] = zero4; }
    for (int ks = 0; ks < 16; ++ks) {
        f16x8 bx0 = *(const f16x8*)(xb + (size_t)li * 512 + ks * 32 + g * 8);
        f16x8 bx1 = *(const f16x8*)(xb + (size_t)(16 + li) * 512 + ks * 32 + g * 8);
#pragma unroll
        for (int mt = 0; mt < 4; ++mt) {
            const f16x8 af = *(const f16x8*)(Wv1h + (size_t)(w * 64 + mt * 16 + li) * 512 + ks * 32 + g * 8);
            a1[mt][0] = mfma16(af, bx0, a1[mt][0]);
            a1[mt][1] = mfma16(af, bx1, a1[mt][1]);
        }
        if (ks < 8) {
            const f16x8 afk = *(const f16x8*)(Wkh + (size_t)(w * 16 + li) * 256 + ks * 32 + g * 8);
            ak[0] = mfma16(afk, bx0, ak[0]);
            ak[1] = mfma16(afk, bx1, ak[1]);
        } else {
            const f16x8 afq = *(const f16x8*)(Wqh + (size_t)(w * 16 + li) * 256 + (ks - 8) * 32 + g * 8);
            aq[0] = mfma16(afq, bx0, aq[0]);
            aq[1] = mfma16(afq, bx1, aq[1]);
        }
    }
    f32x4 au[2] = {zero4, zero4};
    {
        const f16* xub = xuT + ((size_t)b * NN + n0) * 256;
        for (int ks = 0; ks < 8; ++ks) {
            f16x8 bu0 = *(const f16x8*)(xub + (size_t)li * 256 + ks * 32 + g * 8);
            f16x8 bu1 = *(const f16x8*)(xub + (size_t)(16 + li) * 256 + ks * 32 + g * 8);
            const f16x8 af = *(const f16x8*)(Wuh + (size_t)(w * 16 + li) * 256 + ks * 32 + g * 8);
            au[0] = mfma16(af, bu0, au[0]);
            au[1] = mfma16(af, bu1, au[1]);
        }
    }
#pragma unroll
    for (int mt = 0; mt < 4; ++mt) {
        const int ch0 = w * 64 + mt * 16 + g * 4;
        const float4 b4 = *(const float4*)(bv1 + ch0);
#pragma unroll
        for (int nt = 0; nt < 2; ++nt) {
            const int n = nt * 16 + li;
            f16x4 px;
            px.x = (f16)fmaxf(a1[mt][nt][0] + b4.x, 0.f);
            px.y = (f16)fmaxf(a1[mt][nt][1] + b4.y, 0.f);
            px.z = (f16)fmaxf(a1[mt][nt][2] + b4.z, 0.f);
            px.w = (f16)fmaxf(a1[mt][nt][3] + b4.w, 0.f);
            *(f16x4*)(hv + n * 512 + ((ch0 * 2) ^ ((n & 7) << 4))) = px;
        }
    }
    {
        const int ch0 = w * 16 + g * 4;
        const float4 bk4 = *(const float4*)(bk + ch0);
        const float4 bq4 = *(const float4*)(bq + ch0);
        const float4 bu4 = *(const float4*)(bu + ch0);
#pragma unroll
        for (int nt = 0; nt < 2; ++nt) {
            const int n = nt * 16 + li;
            const size_t base = ((size_t)b * NN + n0 + n) * DD + ch0;
            ushort4 pk, pq, pu;
            pk.x = f2bfu(ak[nt][0] + bk4.x); pk.y = f2bfu(ak[nt][1] + bk4.y);
            pk.z = f2bfu(ak[nt][2] + bk4.z); pk.w = f2bfu(ak[nt][3] + bk4.w);
            pq.x = f2bfu(aq[nt][0] + bq4.x); pq.y = f2bfu(aq[nt][1] + bq4.y);
            pq.z = f2bfu(aq[nt][2] + bq4.z); pq.w = f2bfu(aq[nt][3] + bq4.w);
            pu.x = f2bfu(au[nt][0] + bu4.x); pu.y = f2bfu(au[nt][1] + bu4.y);
            pu.z = f2bfu(au[nt][2] + bu4.z); pu.w = f2bfu(au[nt][3] + bu4.w);
            *(ushort4*)((char*)kf + base * 2) = pk;
            *(ushort4*)((char*)qf + base * 2) = pq;
            *(ushort4*)((char*)uf + base * 2) = pu;
        }
    }
    __syncthreads();

    f32x4 a2[4][2];
#pragma unroll
    for (int mt = 0; mt < 4; ++mt) { a2[mt][0] = zero4; a2[mt][1] = zero4; }
    for (int ks = 0; ks < 8; ++ks) {
        f16x8 bh[2];
#pragma unroll
        for (int nt = 0; nt < 2; ++nt) {
            const int n = nt * 16 + li;
            bh[nt] = *(const f16x8*)(hv + n * 512 + ((ks * 64 + g * 16) ^ ((n & 7) << 4)));
        }
#pragma unroll
        for (int mt = 0; mt < 4; ++mt) {
            const f16x8 af = *(const f16x8*)(Wv2h + (size_t)(w * 64 + mt * 16 + li) * 256 + ks * 32 + g * 8);
            a2[mt][0] = mfma16(af, bh[0], a2[mt][0]);
            a2[mt][1] = mfma16(af, bh[1], a2[mt][1]);
        }
    }
    for (int ks = 0; ks < 16; ++ks) {
        f16x8 bx0 = *(const f16x8*)(xb + (size_t)li * 512 + ks * 32 + g * 8);
        f16x8 bx1 = *(const f16x8*)(xb + (size_t)(16 + li) * 512 + ks * 32 + g * 8);
#pragma unroll
        for (int mt = 0; mt < 4; ++mt) {
            const f16x8 af = *(const f16x8*)(Wvsh + (size_t)(w * 64 + mt * 16 + li) * 512 + ks * 32 + g * 8);
            a2[mt][0] = mfma16(af, bx0, a2[mt][0]);
            a2[mt][1] = mfma16(af, bx1, a2[mt][1]);
        }
    }
    __syncthreads();
#pragma unroll
    for (int mt = 0; mt < 4; ++mt) {
        const int ch0 = w * 64 + mt * 16 + g * 4;
        const float4 c4a = *(const float4*)(bv2 + ch0);
        const float4 c4b = *(const float4*)(bvs + ch0);
#pragma unroll
        for (int nt = 0; nt < 2; ++nt) {
            const int n = nt * 16 + li;
            f16x4 px;
            px.x = (f16)(a2[mt][nt][0] + c4a.x + c4b.x);
            px.y = (f16)(a2[mt][nt][1] + c4a.y + c4b.y);
            px.z = (f16)(a2[mt][nt][2] + c4a.z + c4b.z);
            px.w = (f16)(a2[mt][nt][3] + c4a.w + c4b.w);
            *(f16x4*)(hv + n * 512 + ((ch0 * 2) ^ ((n & 7) << 4))) = px;
        }
    }
    __syncthreads();

    f32x4 av[2] = {zero4, zero4};
    f32x4 ar[2][2];
    ar[0][0] = zero4; ar[0][1] = zero4; ar[1][0] = zero4; ar[1][1] = zero4;
    for (int ks = 0; ks < 8; ++ks) {
        f16x8 bh[2];
#pragma unroll
        for (int nt = 0; nt < 2; ++nt) {
            const int n = nt * 16 + li;
            bh[nt] = *(const f16x8*)(hv + n * 512 + ((ks * 64 + g * 16) ^ ((n & 7) << 4)));
        }
        const f16x8 afv = *(const f16x8*)(Wvvh + (size_t)(w * 16 + li) * 256 + ks * 32 + g * 8);
        av[0] = mfma16(afv, bh[0], av[0]);
        av[1] = mfma16(afv, bh[1], av[1]);
#pragma unroll
        for (int rt = 0; rt < 2; ++rt) {
            const f16x8 afr = *(const f16x8*)(Wresh + (size_t)((w * 2 + rt) * 16 + li) * 256 + ks * 32 + g * 8);
            ar[rt][0] = mfma16(afr, bh[0], ar[rt][0]);
            ar[rt][1] = mfma16(afr, bh[1], ar[rt][1]);
        }
    }
    {
        const int ch0 = w * 16 + g * 4;
        const float4 bb = *(const float4*)(bvv + ch0);
#pragma unroll
        for (int nt = 0; nt < 2; ++nt) {
            const int n = nt * 16 + li;
            ushort4 pk;
            pk.x = f2bfu(av[nt][0] + bb.x);
            pk.y = f2bfu(av[nt][1] + bb.y);
            pk.z = f2bfu(av[nt][2] + bb.z);
            pk.w = f2bfu(av[nt][3] + bb.w);
            *(ushort4*)((char*)vf_ws + (((size_t)b * NN + n0 + n) * DD + ch0) * 2) = pk;
        }
    }
#pragma unroll
    for (int rt = 0; rt < 2; ++rt) {
        const int ch0 = (w * 2 + rt) * 16 + g * 4;
        const float4 bb = *(const float4*)(bres + ch0);
#pragma unroll
        for (int nt = 0; nt < 2; ++nt) {
            const int n = nt * 16 + li;
            ushort4 pk;
            pk.x = f2bfu(ar[rt][nt][0] + bb.x);
            pk.y = f2bfu(ar[rt][nt][1] + bb.y);
            pk.z = f2bfu(ar[rt][nt][2] + bb.z);
            pk.w = f2bfu(ar[rt][nt][3] + bb.w);
            *(ushort4*)((char*)resid_ws + (((size_t)b * NN + n0 + n) * COUTN + ch0) * 2) = pk;
        }
    }
}

// ---------------------------------------------------------------------------
// Kernel 4 (fused): 8 n's per block, 8 waves (512 threads) — verified r12
// (NPB=8 + 16B-vectorized gather; best graded total).
// ---------------------------------------------------------------------------
__global__ __launch_bounds__(512, 4) void attn_fused(
    const float* __restrict__ posT, const u16* __restrict__ idx_ws,
    const bf16* __restrict__ kf_ws, const bf16* __restrict__ qf_ws,
    const bf16* __restrict__ uf_ws, const bf16* __restrict__ vf_ws,
    const bf16* __restrict__ resid_ws,
    const float* __restrict__ Wp1, const float* __restrict__ bp1,
    const float* __restrict__ gp1, const float* __restrict__ betap1,
    const f16* __restrict__ Wp2h, const float* __restrict__ bp2,
    const f16* __restrict__ Wa1h, const float* __restrict__ A1s,
    const float* __restrict__ A1b, const f16* __restrict__ Wth,
    const f16* __restrict__ Wendh, const float* __restrict__ bend,
    float* __restrict__ out) {
    __shared__ __align__(16) char pool[61440];
    f16*  ph16 = (f16*)(pool);
    f16*  S16  = (f16*)(pool);            // overlays ph16 (dead after C)
    f16*  L16T = (f16*)(pool);            // overlays S16 (dead after loop)
    f16*  peh  = (f16*)(pool + 20480);
    char* Hl   = pool + 20480;            // overlays peh (dead after D)
    f16*  V16  = (f16*)(pool + 40960);
    __shared__ __align__(16) f16 aggf[16 * 64];   // [nr][c] swizzled
    __shared__ int   nidx[NPB * KK];
    __shared__ float prel[NPB * KK][3];
    __shared__ float qcol[NPB][64], ucol[NPB][64];

    const int b  = blockIdx.x >> 8;           // NN/8 = 256 blocks per batch
    const int n0 = (blockIdx.x & 255) << 3;
    const int t = threadIdx.x;
    const int w = t >> 6, l = t & 63, g = l >> 4, li = l & 15;
    const int m4 = w & 3, nh = w >> 2;
    const size_t row0 = (size_t)b * NN + n0;
    const f32x4 zero4 = {0.f, 0.f, 0.f, 0.f};

    if (t < NPB * KK) nidx[t] = (int)idx_ws[row0 * KK + t];
    __syncthreads();

    // A: per-n q/u columns + prel
    {
        const int n = t >> 6, c = t & 63;
        qcol[n][c] = bf2f(qf_ws[(row0 + n) * DD + c]);
        ucol[n][c] = bf2f(uf_ws[(row0 + n) * DD + c]);
    }
    if (t < 480) {
        const int r = t / 3, d = t - r * 3;
        const int n = r / KK;
        prel[r][d] = posT[(row0 + n) * 3 + d] - posT[((size_t)b * NN + nidx[r]) * 3 + d];
    }
    __syncthreads();

    // B: pos_mlp l1 (3->64, BN, ReLU) -> ph16 packed+swizzled
    for (int u = t; u < 160 * 32; u += 512) {
        const int r = u >> 5, c0 = (u & 31) << 1;
        float a0 = Wp1[c0 * 3 + 0] * prel[r][0] + Wp1[c0 * 3 + 1] * prel[r][1]
                 + Wp1[c0 * 3 + 2] * prel[r][2] + bp1[c0];
        float a1 = Wp1[c0 * 3 + 3] * prel[r][0] + Wp1[c0 * 3 + 4] * prel[r][1]
                 + Wp1[c0 * 3 + 5] * prel[r][2] + bp1[c0 + 1];
        a0 = gp1[c0] * a0 * BN_INV + betap1[c0];
        a1 = gp1[c0 + 1] * a1 * BN_INV + betap1[c0 + 1];
        h2 pr; pr.x = (f16)fmaxf(a0, 0.f); pr.y = (f16)fmaxf(a1, 0.f);
        *(unsigned*)((char*)ph16 + (r * 128 + ((c0 * 2) ^ ((r & 7) << 4)))) =
            __builtin_bit_cast(unsigned, pr);
    }
    __syncthreads();

    // C: pos_mlp l2 via MFMA (M=64 co, N=160 nk, K=64) -> peh[nk][co]+bp2
    {
        f32x4 d[5];
#pragma unroll
        for (int j = 0; j < 5; ++j) d[j] = zero4;
#pragma unroll
        for (int ks = 0; ks < 2; ++ks) {
            const f16x8 af = *(const f16x8*)(Wp2h + (m4 * 16 + li) * 64 + ks * 32 + g * 8);
#pragma unroll
            for (int j = 0; j < 5; ++j) {
                const int r = (nh * 5 + j) * 16 + li;
                const f16x8 bf = *(const f16x8*)((const char*)ph16 +
                                  (r * 128 + ((ks * 64 + g * 16) ^ ((r & 7) << 4))));
                d[j] = mfma16(af, bf, d[j]);
            }
        }
        const int ch0 = m4 * 16 + g * 4;
        const float4 b4 = *(const float4*)(bp2 + ch0);
#pragma unroll
        for (int j = 0; j < 5; ++j) {
            const int r = (nh * 5 + j) * 16 + li;
            f16x4 pk;
            pk.x = (f16)(d[j][0] + b4.x);
            pk.y = (f16)(d[j][1] + b4.y);
            pk.z = (f16)(d[j][2] + b4.z);
            pk.w = (f16)(d[j][3] + b4.w);
            *(f16x4*)((char*)peh + (r * 128 + ((ch0 * 2) ^ ((r & 7) << 4)))) = pk;
        }
    }
    __syncthreads();

    // D: gather + combine, 16B-vectorized (8 channels/chunk) -> S16, V16
    for (int u = t; u < 160 * 8; u += 512) {
        const int r = u >> 3, cg = (u & 7) << 3;
        const int n = r / KK;
        const size_t nb = (((size_t)b * NN + nidx[r]) * DD + cg) * 2;
        const uint4 kq = *(const uint4*)((const char*)kf_ws + nb);
        const uint4 uq = *(const uint4*)((const char*)uf_ws + nb);
        const uint4 vq = *(const uint4*)((const char*)vf_ws + nb);
        const int sw = (cg * 2) ^ ((r & 7) << 4);
        const uint4 pw = *(const uint4*)((const char*)peh + (r * 128 + sw));
        uint4 sres, vres;
#define PROC(comp, off) { \
        const float k0 = lo2f(kq.comp), k1 = hi2f(kq.comp); \
        const float u0 = lo2f(uq.comp), u1 = hi2f(uq.comp); \
        const float v0 = lo2f(vq.comp), v1 = hi2f(vq.comp); \
        const h2 pp = __builtin_bit_cast(h2, pw.comp); \
        const float add0 = ucol[n][cg + off]     + (float)pp.x; \
        const float add1 = ucol[n][cg + off + 1] + (float)pp.y; \
        h2 s; s.x = (f16)(-(k0 + u0) + qcol[n][cg + off] + add0); \
              s.y = (f16)(-(k1 + u1) + qcol[n][cg + off + 1] + add1); \
        h2 v; v.x = (f16)(v0 - u0 + add0); v.y = (f16)(v1 - u1 + add1); \
        sres.comp = __builtin_bit_cast(unsigned, s); \
        vres.comp = __builtin_bit_cast(unsigned, v); }
        PROC(x, 0) PROC(y, 2) PROC(z, 4) PROC(w, 6)
#undef PROC
        *(uint4*)((char*)S16 + (r * 128 + sw)) = sres;
        *(uint4*)((char*)V16 + (r * 128 + sw)) = vres;
    }
    __syncthreads();

    // GEMM loop: 4 chunks of 64 H-rows. GEMM1: wave = (m4 M-tile, nh nt-half);
    // GEMM2: wave w owns cr-tile w, K = chunk's 64 rows.
    f32x4 acc2[10];
#pragma unroll
    for (int j = 0; j < 10; ++j) acc2[j] = zero4;

    for (int c4 = 0; c4 < 4; ++c4) {
        const int hrb = c4 * 64 + m4 * 16;
        f32x4 d1[5];
#pragma unroll
        for (int j = 0; j < 5; ++j) d1[j] = zero4;
#pragma unroll
        for (int ks = 0; ks < 2; ++ks) {
            const f16x8 af = *(const f16x8*)(Wa1h + (hrb + li) * 64 + ks * 32 + g * 8);
#pragma unroll
            for (int j = 0; j < 5; ++j) {
                const int r = (nh * 5 + j) * 16 + li;
                const f16x8 sfv = *(const f16x8*)((const char*)S16 +
                                   (r * 128 + ((ks * 64 + g * 16) ^ ((r & 7) << 4))));
                d1[j] = mfma16(af, sfv, d1[j]);
            }
        }
        const float4 as4 = *(const float4*)(A1s + hrb + g * 4);
        const float4 ab4 = *(const float4*)(A1b + hrb + g * 4);
        __syncthreads();   // prior chunk's GEMM2 (and c4=0: phase D) done
#pragma unroll
        for (int j = 0; j < 5; ++j) {
            const int col = (nh * 5 + j) * 16 + li;
            const int ch0 = m4 * 16 + g * 4;   // chunk-local H row
            f16x4 pk;
            pk.x = (f16)fmaxf(as4.x * d1[j][0] + ab4.x, 0.f);
            pk.y = (f16)fmaxf(as4.y * d1[j][1] + ab4.y, 0.f);
            pk.z = (f16)fmaxf(as4.z * d1[j][2] + ab4.z, 0.f);
            pk.w = (f16)fmaxf(as4.w * d1[j][3] + ab4.w, 0.f);
            *(f16x4*)(Hl + col * 128 + ((ch0 * 2) ^ ((col & 7) << 4))) = pk;
        }
        __syncthreads();
#pragma unroll
        for (int ks2 = 0; ks2 < 2; ++ks2) {
            const f16x8 bf = *(const f16x8*)(Wth + (size_t)(w * 16 + li) * AHH + c4 * 64 + ks2 * 32 + g * 8);
#pragma unroll
            for (int nt = 0; nt < 10; ++nt) {
                const int col = nt * 16 + li;
                const f16x8 ha = *(const f16x8*)(Hl + col * 128 + ((ks2 * 64 + g * 16) ^ ((col & 7) << 4)));
                acc2[nt] = mfma16(ha, bf, acc2[nt]);
            }
        }
    }
    __syncthreads();   // Hl/S16 reads done before L16T overlays

    // logits L16T[row=nk][col=cr], XOR((row&3)<<5)
#pragma unroll
    for (int nt = 0; nt < 10; ++nt) {
        const f32x4 d = acc2[nt];
#pragma unroll
        for (int j = 0; j < 4; ++j) {
            const int row = nt * 16 + g * 4 + j;
            *(f16*)((char*)L16T + (row * 256 + (((w * 16 + li) * 2) ^ ((row & 3) << 5)))) =
                (f16)d[j];
        }
    }
    __syncthreads();

    // softmax over k + aggregate with V16 -> aggf[nr][c] f16 swizzled
    {
        const int cr = t & 127, c = cr >> 1, rr = cr & 1;
        const int nbase = (t >> 7) * 2;
        for (int p = 0; p < 2; ++p) {
            const int n = nbase + p;
            float lv[20];
#pragma unroll
            for (int k = 0; k < 20; ++k) {
                const int row = n * KK + k;
                lv[k] = (float)*(const f16*)((const char*)L16T +
                          (row * 256 + ((cr * 2) ^ ((row & 3) << 5))));
            }
            float m = lv[0];
#pragma unroll
            for (int k = 1; k < 20; ++k) m = fmaxf(m, lv[k]);
            float s = 0.f, a = 0.f;
#pragma unroll
            for (int k = 0; k < 20; ++k) {
                const float e = __expf(lv[k] - m);
                s += e;
                const int r = n * KK + k;
                const float vv = (float)*(const f16*)((const char*)V16 +
                                   (r * 128 + ((c * 2) ^ ((r & 7) << 4))));
                a += e * vv;
            }
            const int arow = n * 2 + rr;
            *(f16*)((char*)aggf + (arow * 128 + ((c * 2) ^ ((arow & 7) << 4)))) = (f16)(a / s);
        }
    }
    __syncthreads();

    // conv_end via MFMA: M=128 o (wave w -> o-tile w), N=16 nr, K=64.
    // D col li -> output offset 2n0+li (64B-coalesced stores).
    {
        f32x4 dc = zero4;
#pragma unroll
        for (int ks = 0; ks < 2; ++ks) {
            const f16x8 af = *(const f16x8*)(Wendh + (size_t)(w * 16 + li) * 64 + ks * 32 + g * 8);
            const f16x8 bfr = *(const f16x8*)((const char*)aggf +
                               (li * 128 + (((ks * 32 + g * 8) * 2) ^ ((li & 7) << 4))));
            dc = mfma16(af, bfr, dc);
        }
        const int nloc = li >> 1;
#pragma unroll
        for (int j = 0; j < 4; ++j) {
            const int o = w * 16 + g * 4 + j;
            const float rv = bf2f(resid_ws[(row0 + nloc) * COUTN + o]);
            out[(size_t)b * COUTN * (NN * UPF) + (size_t)o * (NN * UPF) + 2 * n0 + li] =
                dc[j] + bend[o] + rv;
        }
    }
}

extern "C" void kernel_launch(void* const* d_in, const int* in_sizes, int n_in,
                              void* d_out, int out_size, void* d_ws, size_t ws_size,
                              hipStream_t stream) {
    const float* pos        = (const float*)d_in[0];
    const float* key_feat   = (const float*)d_in[1];
    const float* query_feat = (const float*)d_in[2];
    const float* upfeat     = (const float*)d_in[3];
    const float* Wv1 = (const float*)d_in[4];
    const float* bv1 = (const float*)d_in[5];
    const float* Wv2 = (const float*)d_in[6];
    const float* bv2 = (const float*)d_in[7];
    const float* Wvs = (const float*)d_in[8];
    const float* bvs = (const float*)d_in[9];
    const float* Wk  = (const float*)d_in[10];
    const float* bk  = (const float*)d_in[11];
    const float* Wq  = (const float*)d_in[12];
    const float* bq  = (const float*)d_in[13];
    const float* Wvv = (const float*)d_in[14];
    const float* bvv = (const float*)d_in[15];
    const float* Wu  = (const float*)d_in[16];
    const float* bu  = (const float*)d_in[17];
    const float* Wp1 = (const float*)d_in[18];
    const float* bp1 = (const float*)d_in[19];
    const float* gp1 = (const float*)d_in[20];
    const float* betap1 = (const float*)d_in[21];
    const float* Wp2 = (const float*)d_in[22];
    const float* bp2 = (const float*)d_in[23];
    const float* Wa1 = (const float*)d_in[24];
    const float* ba1 = (const float*)d_in[25];
    const float* ga1 = (const float*)d_in[26];
    const float* betaa1 = (const float*)d_in[27];
    const float* Wt   = (const float*)d_in[28];
    const float* bt   = (const float*)d_in[29];
    const float* Wend = (const float*)d_in[30];
    const float* bend = (const float*)d_in[31];
    const float* Wres = (const float*)d_in[32];
    const float* bres = (const float*)d_in[33];
    float* out = (float*)d_out;
    (void)out_size; (void)bt;   // bt cancels in softmax (uniform over k)

    const bool sizes_ok = (n_in >= 34)
        && (in_sizes[0] == BB * 3 * NN)
        && (in_sizes[1] == BB * CIN * NN)
        && (in_sizes[4] == CIN * 2 * CIN)
        && (in_sizes[28] == AHH * DD * UPF)
        && (in_sizes[32] == COUTN * CIN);

    size_t off = 0;
    auto take = [&](size_t bytes) { size_t o = off; off = (off + bytes + 255) & ~(size_t)255; return o; };
    const size_t off_posT  = take((size_t)BB * NN * 3 * sizeof(float));
    const size_t off_idx   = take((size_t)BB * NN * KK * sizeof(u16));
    const size_t off_vf    = take((size_t)BB * NN * DD * sizeof(bf16));
    const size_t off_kf    = take((size_t)BB * NN * DD * sizeof(bf16));
    const size_t off_qf    = take((size_t)BB * NN * DD * sizeof(bf16));
    const size_t off_uf    = take((size_t)BB * NN * DD * sizeof(bf16));
    const size_t off_resid = take((size_t)BB * NN * COUTN * sizeof(bf16));
    const size_t off_wa1h  = take((size_t)AHH * DD * sizeof(f16));
    const size_t off_wp2h  = take((size_t)PHH * DD * sizeof(f16));
    const size_t off_wth   = take((size_t)COUTN * AHH * sizeof(f16));
    const size_t off_a1s   = take((size_t)AHH * sizeof(float));
    const size_t off_a1b   = take((size_t)AHH * sizeof(float));
    const size_t off_wendh = take((size_t)COUTN * DD * sizeof(f16));
    const size_t off_wv1h  = take((size_t)CIN * 2 * CIN * sizeof(f16));
    const size_t off_wv2h  = take((size_t)CIN * CIN * sizeof(f16));
    const size_t off_wvsh  = take((size_t)CIN * 2 * CIN * sizeof(f16));
    const size_t off_wvvh  = take((size_t)DD * CIN * sizeof(f16));
    const size_t off_wresh = take((size_t)COUTN * CIN * sizeof(f16));
    const size_t off_wkh   = take((size_t)DD * CIN * sizeof(f16));
    const size_t off_wqh   = take((size_t)DD * CIN * sizeof(f16));
    const size_t off_wuh   = take((size_t)DD * CIN * sizeof(f16));
    const size_t off_xkq   = take((size_t)BB * NN * 512 * sizeof(f16));
    const size_t off_xu    = take((size_t)BB * NN * 256 * sizeof(f16));
    const size_t NEED = off;

    if (!sizes_ok) return;
    if (ws_size < NEED) {
        sentinel_kernel<<<1, 64, 0, stream>>>(out);
        return;
    }

    char* ws = (char*)d_ws;
    float* posT_ws  = (float*)(ws + off_posT);
    u16*   idx_ws   = (u16*)(ws + off_idx);
    bf16*  vf_ws    = (bf16*)(ws + off_vf);
    bf16*  kf_ws    = (bf16*)(ws + off_kf);
    bf16*  qf_ws    = (bf16*)(ws + off_qf);
    bf16*  uf_ws    = (bf16*)(ws + off_uf);
    bf16*  resid_ws = (bf16*)(ws + off_resid);
    f16*   Wa1h_ws  = (f16*)(ws + off_wa1h);
    f16*   Wp2h_ws  = (f16*)(ws + off_wp2h);
    f16*   Wth_ws   = (f16*)(ws + off_wth);
    float* A1s_ws   = (float*)(ws + off_a1s);
    float* A1b_ws   = (float*)(ws + off_a1b);
    f16*   Wendh_ws = (f16*)(ws + off_wendh);
    f16*   Wv1h_ws  = (f16*)(ws + off_wv1h);
    f16*   Wv2h_ws  = (f16*)(ws + off_wv2h);
    f16*   Wvsh_ws  = (f16*)(ws + off_wvsh);
    f16*   Wvvh_ws  = (f16*)(ws + off_wvvh);
    f16*   Wresh_ws = (f16*)(ws + off_wresh);
    f16*   Wkh_ws   = (f16*)(ws + off_wkh);
    f16*   Wqh_ws   = (f16*)(ws + off_wqh);
    f16*   Wuh_ws   = (f16*)(ws + off_wuh);
    f16*   xkqT_ws  = (f16*)(ws + off_xkq);
    f16*   xuT_ws   = (f16*)(ws + off_xu);

    prep_kernel<<<(CIN * 2 * CIN + 255) / 256, 256, 0, stream>>>(
        Wa1, Wp2, Wend, Wt, Wv1, Wv2, Wvs, Wvv, Wres, Wk, Wq, Wu,
        ba1, ga1, betaa1,
        Wa1h_ws, Wp2h_ws, Wth_ws, A1s_ws, A1b_ws, Wendh_ws,
        Wv1h_ws, Wv2h_ws, Wvsh_ws, Wvvh_ws, Wresh_ws, Wkh_ws, Wqh_ws, Wuh_ws);
    xpose_kernel<<<dim3(BB * (NN / 64), 12), 256, 0, stream>>>(
        key_feat, query_feat, upfeat, xkqT_ws, xuT_ws);
    knn_kernel<<<BB * NN, 256, 0, stream>>>(pos, idx_ws, posT_ws);
    value_mfma<<<BB * (NN / 32), 256, 0, stream>>>(xkqT_ws, xuT_ws,
        Wv1h_ws, bv1, Wv2h_ws, bv2, Wvsh_ws, bvs, Wvvh_ws, bvv, Wresh_ws, bres,
        Wkh_ws, bk, Wqh_ws, bq, Wuh_ws, bu,
        vf_ws, resid_ws, kf_ws, qf_ws, uf_ws);
    attn_fused<<<BB * (NN / NPB), 512, 0, stream>>>(posT_ws, idx_ws,
        kf_ws, qf_ws, uf_ws, vf_ws, resid_ws,
        Wp1, bp1, gp1, betap1, Wp2h_ws, bp2,
        Wa1h_ws, A1s_ws, A1b_ws, Wth_ws, Wendh_ws, bend, out);
}